// Round 1
// baseline (1395.958 us; speedup 1.0000x reference)
//
#include <hip/hip_runtime.h>
#include <math.h>

#define N_NODES 100000
#define N_EDGES 1600000

__global__ __launch_bounds__(256) void count_deg(const int* __restrict__ dst,
                                                 int* __restrict__ cnt) {
    int e = blockIdx.x * 256 + threadIdx.x;
    if (e < N_EDGES) atomicAdd(&cnt[dst[e]], 1);
}

__global__ __launch_bounds__(256) void make_dinv(const int* __restrict__ cnt,
                                                 float* __restrict__ dinv) {
    int i = blockIdx.x * 256 + threadIdx.x;
    if (i < N_NODES) dinv[i] = rsqrtf((float)(cnt[i] + 1));
}

// Y[i,:] = (X[i,:] @ W) * dinv[i].  X: [nrows,128], W: [128,KOUT]
template<int KOUT>
__global__ __launch_bounds__(256) void gemm_scale(const float* __restrict__ X,
                                                  const float* __restrict__ W,
                                                  const float* __restrict__ dinv,
                                                  float* __restrict__ Y,
                                                  int nrows) {
    constexpr int ROWS = 64;
    constexpr int CPT  = 4;            // cols per thread
    constexpr int CT   = KOUT / CPT;   // col-thread count (32 or 16)
    constexpr int RPT  = ROWS * CT / 256; // rows per thread (8 or 4)
    __shared__ float Ws[128 * KOUT];
    __shared__ float Xs[ROWS][132];    // pad 132: keeps float4 align, breaks bank stride
    const int t = threadIdx.x;
    const int row0 = blockIdx.x * ROWS;

    for (int i = t * 4; i < 128 * KOUT; i += 256 * 4)
        *(float4*)(Ws + i) = *(const float4*)(W + i);
    for (int i = t; i < ROWS * 32; i += 256) {
        int r = i >> 5, c4 = (i & 31) * 4;
        int gr = row0 + r;
        float4 v = make_float4(0.f, 0.f, 0.f, 0.f);
        if (gr < nrows) v = *(const float4*)(X + gr * 128 + c4);
        *(float4*)(&Xs[r][c4]) = v;
    }
    __syncthreads();

    const int tx = t % CT, ty = t / CT;
    const int c0 = tx * CPT;
    float acc[RPT][CPT];
#pragma unroll
    for (int r = 0; r < RPT; ++r)
#pragma unroll
        for (int c = 0; c < CPT; ++c) acc[r][c] = 0.f;

    for (int k = 0; k < 128; k += 4) {
        float4 w0 = *(const float4*)(&Ws[(k + 0) * KOUT + c0]);
        float4 w1 = *(const float4*)(&Ws[(k + 1) * KOUT + c0]);
        float4 w2 = *(const float4*)(&Ws[(k + 2) * KOUT + c0]);
        float4 w3 = *(const float4*)(&Ws[(k + 3) * KOUT + c0]);
#pragma unroll
        for (int r = 0; r < RPT; ++r) {
            float4 xv = *(const float4*)(&Xs[ty * RPT + r][k]);
            acc[r][0] += xv.x * w0.x + xv.y * w1.x + xv.z * w2.x + xv.w * w3.x;
            acc[r][1] += xv.x * w0.y + xv.y * w1.y + xv.z * w2.y + xv.w * w3.y;
            acc[r][2] += xv.x * w0.z + xv.y * w1.z + xv.z * w2.z + xv.w * w3.z;
            acc[r][3] += xv.x * w0.w + xv.y * w1.w + xv.z * w2.w + xv.w * w3.w;
        }
    }
#pragma unroll
    for (int r = 0; r < RPT; ++r) {
        int gr = row0 + ty * RPT + r;
        if (gr < nrows) {
            float s = dinv[gr];
            float4 o = make_float4(acc[r][0] * s, acc[r][1] * s, acc[r][2] * s, acc[r][3] * s);
            *(float4*)(Y + gr * KOUT + c0) = o;
        }
    }
}

template<int K, int LOGK>
__global__ __launch_bounds__(256) void scatter_add(const int* __restrict__ src,
                                                   const int* __restrict__ dst,
                                                   const float* __restrict__ Y,
                                                   float* __restrict__ agg) {
    int gid = blockIdx.x * 256 + threadIdx.x;
    int e = gid >> LOGK;
    int f = gid & (K - 1);
    if (e < N_EDGES) {
        int s = src[e], d = dst[e];
        atomicAdd(&agg[d * K + f], Y[s * K + f]);
    }
}

// h = relu(dinv[r]*(agg + y) + b)   in-place over agg
__global__ __launch_bounds__(256) void finalize_relu(float* __restrict__ agg,
                                                     const float* __restrict__ Y,
                                                     const float* __restrict__ dinv,
                                                     const float* __restrict__ b) {
    int i = blockIdx.x * 256 + threadIdx.x;
    if (i < N_NODES * 128) {
        int r = i >> 7, f = i & 127;
        float v = dinv[r] * (agg[i] + Y[i]) + b[f];
        agg[i] = fmaxf(v, 0.f);
    }
}

// out = log_softmax(dinv[r]*(agg + y) + b) over 64 cols; one wave per row
__global__ __launch_bounds__(256) void finalize_lsm(const float* __restrict__ agg,
                                                    const float* __restrict__ Y,
                                                    const float* __restrict__ dinv,
                                                    const float* __restrict__ b,
                                                    float* __restrict__ out) {
    int t = threadIdx.x;
    int lane = t & 63, w = t >> 6;
    int r = blockIdx.x * 4 + w;
    if (r >= N_NODES) return;
    int idx = r * 64 + lane;
    float v = dinv[r] * (agg[idx] + Y[idx]) + b[lane];
    float m = v;
#pragma unroll
    for (int o = 32; o; o >>= 1) m = fmaxf(m, __shfl_xor(m, o));
    float ex = __expf(v - m);
    float s = ex;
#pragma unroll
    for (int o = 32; o; o >>= 1) s += __shfl_xor(s, o);
    out[idx] = v - m - logf(s);
}

extern "C" void kernel_launch(void* const* d_in, const int* in_sizes, int n_in,
                              void* d_out, int out_size, void* d_ws, size_t ws_size,
                              hipStream_t stream) {
    const float* x  = (const float*)d_in[0];
    const float* W1 = (const float*)d_in[1];
    const float* b1 = (const float*)d_in[2];
    const float* W2 = (const float*)d_in[3];
    const float* b2 = (const float*)d_in[4];
    const int* edge = (const int*)d_in[5];
    const int* src = edge;             // edge_index[0]
    const int* dst = edge + N_EDGES;   // edge_index[1]
    float* out = (float*)d_out;

    char* ws = (char*)d_ws;
    int*   cnt  = (int*)(ws + 0);                       // 400 KB
    float* dinv = (float*)(ws + 400128);                // 400 KB
    float* y1   = (float*)(ws + 1048576);               // 51.2 MB
    float* agg1 = (float*)(ws + 52248576);              // 51.2 MB (becomes h1)
    float* y2   = y1;                                    // reuse (y1 dead after finalize_relu)
    float* agg2 = (float*)(ws + 26648576);              // second half of y1 region

    hipMemsetAsync(cnt, 0, N_NODES * sizeof(int), stream);
    count_deg<<<(N_EDGES + 255) / 256, 256, 0, stream>>>(dst, cnt);
    make_dinv<<<(N_NODES + 255) / 256, 256, 0, stream>>>(cnt, dinv);

    // ---- layer 1 ----
    hipMemsetAsync(agg1, 0, (size_t)N_NODES * 128 * sizeof(float), stream);
    gemm_scale<128><<<(N_NODES + 63) / 64, 256, 0, stream>>>(x, W1, dinv, y1, N_NODES);
    scatter_add<128, 7><<<(N_EDGES * 128) / 256, 256, 0, stream>>>(src, dst, y1, agg1);
    finalize_relu<<<(N_NODES * 128) / 256 + 1, 256, 0, stream>>>(agg1, y1, dinv, b1);

    // ---- layer 2 ----
    gemm_scale<64><<<(N_NODES + 63) / 64, 256, 0, stream>>>(agg1, W2, dinv, y2, N_NODES);
    hipMemsetAsync(agg2, 0, (size_t)N_NODES * 64 * sizeof(float), stream);
    scatter_add<64, 6><<<(N_EDGES * 64) / 256, 256, 0, stream>>>(src, dst, y2, agg2);
    finalize_lsm<<<(N_NODES + 3) / 4, 256, 0, stream>>>(agg2, y2, dinv, b2, out);
}

// Round 2
// 588.812 us; speedup vs baseline: 2.3708x; 2.3708x over previous
//
#include <hip/hip_runtime.h>
#include <math.h>

#define N_NODES 100000
#define N_EDGES 1600000
#define SCAN_B 391   // ceil(N_NODES/256)

// ---------- degree / dinv ----------
__global__ __launch_bounds__(256) void count_deg(const int* __restrict__ dst,
                                                 int* __restrict__ cnt) {
    int e = blockIdx.x * 256 + threadIdx.x;
    if (e < N_EDGES) atomicAdd(&cnt[dst[e]], 1);
}

__global__ __launch_bounds__(256) void make_dinv(const int* __restrict__ cnt,
                                                 float* __restrict__ dinv) {
    int i = blockIdx.x * 256 + threadIdx.x;
    if (i < N_NODES) dinv[i] = rsqrtf((float)(cnt[i] + 1));
}

// ---------- exclusive scan (3 kernels) ----------
__global__ __launch_bounds__(256) void scan_reduce(const int* __restrict__ cnt,
                                                   int* __restrict__ part) {
    __shared__ int s[256];
    int t = threadIdx.x, i = blockIdx.x * 256 + t;
    s[t] = (i < N_NODES) ? cnt[i] : 0;
    __syncthreads();
    for (int off = 128; off; off >>= 1) {
        if (t < off) s[t] += s[t + off];
        __syncthreads();
    }
    if (!t) part[blockIdx.x] = s[0];
}

__global__ __launch_bounds__(512) void scan_part(int* __restrict__ part) {
    __shared__ int s[512];
    int t = threadIdx.x;
    int v = (t < SCAN_B) ? part[t] : 0;
    s[t] = v;
    __syncthreads();
    for (int off = 1; off < 512; off <<= 1) {
        int u = (t >= off) ? s[t - off] : 0;
        __syncthreads();
        s[t] += u;
        __syncthreads();
    }
    if (t < SCAN_B) part[t] = s[t] - v;  // exclusive
}

__global__ __launch_bounds__(256) void scan_final(const int* __restrict__ cnt,
                                                  const int* __restrict__ part,
                                                  int* __restrict__ rowp) {
    __shared__ int s[256];
    int t = threadIdx.x, i = blockIdx.x * 256 + t;
    int v = (i < N_NODES) ? cnt[i] : 0;
    s[t] = v;
    __syncthreads();
    for (int off = 1; off < 256; off <<= 1) {
        int u = (t >= off) ? s[t - off] : 0;
        __syncthreads();
        s[t] += u;
        __syncthreads();
    }
    if (i < N_NODES) rowp[i] = part[blockIdx.x] + s[t] - v;  // exclusive
    if (i == 0) rowp[N_NODES] = N_EDGES;
}

// ---------- counting-sort fill: srcs grouped by dst ----------
__global__ __launch_bounds__(256) void fill_csr(const int* __restrict__ src,
                                                const int* __restrict__ dst,
                                                const int* __restrict__ rowp,
                                                int* __restrict__ fill,
                                                int* __restrict__ srcs) {
    int e = blockIdx.x * 256 + threadIdx.x;
    if (e < N_EDGES) {
        int d = dst[e];
        int p = rowp[d] + atomicAdd(&fill[d], 1);
        srcs[p] = src[e];
    }
}

// ---------- GEMM with fused dinv scale: Y = (X @ W) * dinv ----------
template<int KOUT>
__global__ __launch_bounds__(256) void gemm_scale(const float* __restrict__ X,
                                                  const float* __restrict__ W,
                                                  const float* __restrict__ dinv,
                                                  float* __restrict__ Y,
                                                  int nrows) {
    constexpr int ROWS = 64;
    constexpr int CPT  = 4;
    constexpr int CT   = KOUT / CPT;
    constexpr int RPT  = ROWS * CT / 256;
    __shared__ float Ws[128 * KOUT];
    __shared__ float Xs[ROWS][132];
    const int t = threadIdx.x;
    const int row0 = blockIdx.x * ROWS;

    for (int i = t * 4; i < 128 * KOUT; i += 256 * 4)
        *(float4*)(Ws + i) = *(const float4*)(W + i);
    for (int i = t; i < ROWS * 32; i += 256) {
        int r = i >> 5, c4 = (i & 31) * 4;
        int gr = row0 + r;
        float4 v = make_float4(0.f, 0.f, 0.f, 0.f);
        if (gr < nrows) v = *(const float4*)(X + gr * 128 + c4);
        *(float4*)(&Xs[r][c4]) = v;
    }
    __syncthreads();

    const int tx = t % CT, ty = t / CT;
    const int c0 = tx * CPT;
    float acc[RPT][CPT];
#pragma unroll
    for (int r = 0; r < RPT; ++r)
#pragma unroll
        for (int c = 0; c < CPT; ++c) acc[r][c] = 0.f;

    for (int k = 0; k < 128; k += 4) {
        float4 w0 = *(const float4*)(&Ws[(k + 0) * KOUT + c0]);
        float4 w1 = *(const float4*)(&Ws[(k + 1) * KOUT + c0]);
        float4 w2 = *(const float4*)(&Ws[(k + 2) * KOUT + c0]);
        float4 w3 = *(const float4*)(&Ws[(k + 3) * KOUT + c0]);
#pragma unroll
        for (int r = 0; r < RPT; ++r) {
            float4 xv = *(const float4*)(&Xs[ty * RPT + r][k]);
            acc[r][0] += xv.x * w0.x + xv.y * w1.x + xv.z * w2.x + xv.w * w3.x;
            acc[r][1] += xv.x * w0.y + xv.y * w1.y + xv.z * w2.y + xv.w * w3.y;
            acc[r][2] += xv.x * w0.z + xv.y * w1.z + xv.z * w2.z + xv.w * w3.z;
            acc[r][3] += xv.x * w0.w + xv.y * w1.w + xv.z * w2.w + xv.w * w3.w;
        }
    }
#pragma unroll
    for (int r = 0; r < RPT; ++r) {
        int gr = row0 + ty * RPT + r;
        if (gr < nrows) {
            float s = dinv[gr];
            float4 o = make_float4(acc[r][0] * s, acc[r][1] * s, acc[r][2] * s, acc[r][3] * s);
            *(float4*)(Y + gr * KOUT + c0) = o;
        }
    }
}

// ---------- CSR aggregation, K=128, fused self-loop+dinv+bias+ReLU ----------
// one wave per node, float2 per lane
__global__ __launch_bounds__(256) void agg_relu(const int* __restrict__ rowp,
                                                const int* __restrict__ srcs,
                                                const float* __restrict__ Y,
                                                const float* __restrict__ dinv,
                                                const float* __restrict__ b,
                                                float* __restrict__ H) {
    int t = threadIdx.x;
    int lane = t & 63, w = t >> 6;
    int d = blockIdx.x * 4 + w;
    if (d >= N_NODES) return;
    const float2* Y2 = (const float2*)Y;
    float2 acc = Y2[(size_t)d * 64 + lane];  // self loop
    int e = rowp[d], end = rowp[d + 1];
    for (; e + 4 <= end; e += 4) {
        int s0 = srcs[e], s1 = srcs[e + 1], s2 = srcs[e + 2], s3 = srcs[e + 3];
        float2 a0 = Y2[(size_t)s0 * 64 + lane];
        float2 a1 = Y2[(size_t)s1 * 64 + lane];
        float2 a2 = Y2[(size_t)s2 * 64 + lane];
        float2 a3 = Y2[(size_t)s3 * 64 + lane];
        acc.x += (a0.x + a1.x) + (a2.x + a3.x);
        acc.y += (a0.y + a1.y) + (a2.y + a3.y);
    }
    for (; e < end; ++e) {
        float2 a = Y2[(size_t)srcs[e] * 64 + lane];
        acc.x += a.x;
        acc.y += a.y;
    }
    float s = dinv[d];
    float2 bb = ((const float2*)b)[lane];
    float2 o;
    o.x = fmaxf(s * acc.x + bb.x, 0.f);
    o.y = fmaxf(s * acc.y + bb.y, 0.f);
    ((float2*)H)[(size_t)d * 64 + lane] = o;
}

// ---------- CSR aggregation, K=64, fused log_softmax ----------
__global__ __launch_bounds__(256) void agg_lsm(const int* __restrict__ rowp,
                                               const int* __restrict__ srcs,
                                               const float* __restrict__ Y,
                                               const float* __restrict__ dinv,
                                               const float* __restrict__ b,
                                               float* __restrict__ out) {
    int t = threadIdx.x;
    int lane = t & 63, w = t >> 6;
    int d = blockIdx.x * 4 + w;
    if (d >= N_NODES) return;
    float acc = Y[(size_t)d * 64 + lane];  // self loop
    int e = rowp[d], end = rowp[d + 1];
    for (; e + 4 <= end; e += 4) {
        int s0 = srcs[e], s1 = srcs[e + 1], s2 = srcs[e + 2], s3 = srcs[e + 3];
        acc += (Y[(size_t)s0 * 64 + lane] + Y[(size_t)s1 * 64 + lane]) +
               (Y[(size_t)s2 * 64 + lane] + Y[(size_t)s3 * 64 + lane]);
    }
    for (; e < end; ++e) acc += Y[(size_t)srcs[e] * 64 + lane];
    float v = dinv[d] * acc + b[lane];
    float m = v;
#pragma unroll
    for (int o = 32; o; o >>= 1) m = fmaxf(m, __shfl_xor(m, o));
    float ex = __expf(v - m);
    float su = ex;
#pragma unroll
    for (int o = 32; o; o >>= 1) su += __shfl_xor(su, o);
    out[(size_t)d * 64 + lane] = v - m - logf(su);
}

extern "C" void kernel_launch(void* const* d_in, const int* in_sizes, int n_in,
                              void* d_out, int out_size, void* d_ws, size_t ws_size,
                              hipStream_t stream) {
    const float* x  = (const float*)d_in[0];
    const float* W1 = (const float*)d_in[1];
    const float* b1 = (const float*)d_in[2];
    const float* W2 = (const float*)d_in[3];
    const float* b2 = (const float*)d_in[4];
    const int* edge = (const int*)d_in[5];
    const int* src = edge;
    const int* dst = edge + N_EDGES;
    float* out = (float*)d_out;

    char* ws = (char*)d_ws;
    int*   cnt   = (int*)(ws + 0);         // 400000 B
    int*   fill  = (int*)(ws + 400000);    // 400000 B  (adjacent to cnt: one memset)
    float* dinv  = (float*)(ws + 800000);  // 400000 B
    int*   rowp  = (int*)(ws + 1200000);   // 400004 B
    int*   part  = (int*)(ws + 1600064);   // 1564 B
    int*   srcs  = (int*)(ws + 1601664);   // 6.4 MB
    float* y1    = (float*)(ws + 8388608);   // 51.2 MB
    float* h1    = (float*)(ws + 60817408);  // 51.2 MB
    float* y2    = y1;  // y1 dead after agg_relu

    // ---- build CSR (dst-grouped src list) + dinv ----
    hipMemsetAsync(cnt, 0, 800000, stream);  // cnt + fill
    count_deg<<<(N_EDGES + 255) / 256, 256, 0, stream>>>(dst, cnt);
    make_dinv<<<(N_NODES + 255) / 256, 256, 0, stream>>>(cnt, dinv);
    scan_reduce<<<SCAN_B, 256, 0, stream>>>(cnt, part);
    scan_part<<<1, 512, 0, stream>>>(part);
    scan_final<<<SCAN_B, 256, 0, stream>>>(cnt, part, rowp);
    fill_csr<<<(N_EDGES + 255) / 256, 256, 0, stream>>>(src, dst, rowp, fill, srcs);

    // ---- layer 1 ----
    gemm_scale<128><<<(N_NODES + 63) / 64, 256, 0, stream>>>(x, W1, dinv, y1, N_NODES);
    agg_relu<<<(N_NODES + 3) / 4, 256, 0, stream>>>(rowp, srcs, y1, dinv, b1, h1);

    // ---- layer 2 ----
    gemm_scale<64><<<(N_NODES + 63) / 64, 256, 0, stream>>>(h1, W2, dinv, y2, N_NODES);
    agg_lsm<<<(N_NODES + 3) / 4, 256, 0, stream>>>(rowp, srcs, y2, dinv, b2, out);
}

// Round 3
// 536.933 us; speedup vs baseline: 2.5999x; 1.0966x over previous
//
#include <hip/hip_runtime.h>
#include <math.h>

#define N_NODES 100000
#define N_EDGES 1600000
#define SCAN_B 391          // ceil(N_NODES/256)
#define MROWS 100096        // 782*128, padded row count for guard-free loads

typedef __attribute__((ext_vector_type(8))) short short8;  // 8 bf16 = 4 VGPRs
typedef __attribute__((ext_vector_type(4))) float f32x4;

__device__ __forceinline__ short f2b(float f) {            // fp32 -> bf16 RNE
    unsigned u = __float_as_uint(f);
    unsigned r = (u + 0x7FFFu + ((u >> 16) & 1u)) >> 16;
    return (short)r;
}
__device__ __forceinline__ float b2f(short s) {
    return __uint_as_float(((unsigned)(unsigned short)s) << 16);
}

// ---------- degree / dinv ----------
__global__ __launch_bounds__(256) void count_deg(const int* __restrict__ dst,
                                                 int* __restrict__ cnt) {
    int e = blockIdx.x * 256 + threadIdx.x;
    if (e < N_EDGES) atomicAdd(&cnt[dst[e]], 1);
}

__global__ __launch_bounds__(256) void make_dinv(const int* __restrict__ cnt,
                                                 float* __restrict__ dinv) {
    int i = blockIdx.x * 256 + threadIdx.x;
    if (i < N_NODES) dinv[i] = rsqrtf((float)(cnt[i] + 1));
}

// ---------- exclusive scan (3 kernels) ----------
__global__ __launch_bounds__(256) void scan_reduce(const int* __restrict__ cnt,
                                                   int* __restrict__ part) {
    __shared__ int s[256];
    int t = threadIdx.x, i = blockIdx.x * 256 + t;
    s[t] = (i < N_NODES) ? cnt[i] : 0;
    __syncthreads();
    for (int off = 128; off; off >>= 1) {
        if (t < off) s[t] += s[t + off];
        __syncthreads();
    }
    if (!t) part[blockIdx.x] = s[0];
}

__global__ __launch_bounds__(512) void scan_part(int* __restrict__ part) {
    __shared__ int s[512];
    int t = threadIdx.x;
    int v = (t < SCAN_B) ? part[t] : 0;
    s[t] = v;
    __syncthreads();
    for (int off = 1; off < 512; off <<= 1) {
        int u = (t >= off) ? s[t - off] : 0;
        __syncthreads();
        s[t] += u;
        __syncthreads();
    }
    if (t < SCAN_B) part[t] = s[t] - v;  // exclusive
}

__global__ __launch_bounds__(256) void scan_final(const int* __restrict__ cnt,
                                                  const int* __restrict__ part,
                                                  int* __restrict__ rowp) {
    __shared__ int s[256];
    int t = threadIdx.x, i = blockIdx.x * 256 + t;
    int v = (i < N_NODES) ? cnt[i] : 0;
    s[t] = v;
    __syncthreads();
    for (int off = 1; off < 256; off <<= 1) {
        int u = (t >= off) ? s[t - off] : 0;
        __syncthreads();
        s[t] += u;
        __syncthreads();
    }
    if (i < N_NODES) rowp[i] = part[blockIdx.x] + s[t] - v;  // exclusive
    if (i == 0) rowp[N_NODES] = N_EDGES;
}

// ---------- counting-sort fill: srcs grouped by dst ----------
__global__ __launch_bounds__(256) void fill_csr(const int* __restrict__ src,
                                                const int* __restrict__ dst,
                                                const int* __restrict__ rowp,
                                                int* __restrict__ fill,
                                                int* __restrict__ srcs) {
    int e = blockIdx.x * 256 + threadIdx.x;
    if (e < N_EDGES) {
        int d = dst[e];
        int p = rowp[d] + atomicAdd(&fill[d], 1);
        srcs[p] = src[e];
    }
}

// ---------- fp32 -> split bf16 (hi, lo) ----------
__global__ __launch_bounds__(256) void convert_split(const float* __restrict__ X,
                                                     short* __restrict__ Hi,
                                                     short* __restrict__ Lo,
                                                     int n4) {
    int i = blockIdx.x * 256 + threadIdx.x;
    if (i < n4) {
        float4 v = ((const float4*)X)[i];
        short h0 = f2b(v.x), h1 = f2b(v.y), h2 = f2b(v.z), h3 = f2b(v.w);
        short l0 = f2b(v.x - b2f(h0)), l1 = f2b(v.y - b2f(h1));
        short l2 = f2b(v.z - b2f(h2)), l3 = f2b(v.w - b2f(h3));
        ushort4 hv = make_ushort4((unsigned short)h0, (unsigned short)h1,
                                  (unsigned short)h2, (unsigned short)h3);
        ushort4 lv = make_ushort4((unsigned short)l0, (unsigned short)l1,
                                  (unsigned short)l2, (unsigned short)l3);
        ((ushort4*)Hi)[i] = hv;
        ((ushort4*)Lo)[i] = lv;
    }
}

// ---------- W [128][N] fp32 -> Wt [N][128] split bf16 ----------
template<int N>
__global__ __launch_bounds__(256) void convert_wt(const float* __restrict__ W,
                                                  short* __restrict__ Whi,
                                                  short* __restrict__ Wlo) {
    int id = blockIdx.x * 256 + threadIdx.x;
    if (id < N * 128) {
        int n = id >> 7, k = id & 127;
        float v = W[k * N + n];
        short h = f2b(v);
        Whi[id] = h;
        Wlo[id] = f2b(v - b2f(h));
    }
}

// ---------- MFMA GEMM: Y[M][N] = (X @ W) * dinv, split-bf16 3-term ----------
// X: [MROWS][128] bf16 hi/lo row-major; Wt: [N][128] bf16 hi/lo (pre-transposed)
template<int N>
__global__ __launch_bounds__(256) void gemm_mfma(const short* __restrict__ Xhi,
                                                 const short* __restrict__ Xlo,
                                                 const short* __restrict__ Wthi,
                                                 const short* __restrict__ Wtlo,
                                                 const float* __restrict__ dinv,
                                                 float* __restrict__ Y) {
    constexpr int NT = N / 16;
    const int t = threadIdx.x;
    const int w = t >> 6, lane = t & 63;
    const int m = lane & 15, q = lane >> 4;
    const int r0 = blockIdx.x * 128 + w * 32;   // wave covers 32 rows, all N cols

    f32x4 acc[2][NT];
#pragma unroll
    for (int i = 0; i < 2; ++i)
#pragma unroll
        for (int c = 0; c < NT; ++c) acc[i][c] = (f32x4)(0.f);

#pragma unroll
    for (int kk = 0; kk < 4; ++kk) {
        const int koff = kk * 32 + q * 8;
        short8 ah0 = *(const short8*)(Xhi + (size_t)(r0 + m) * 128 + koff);
        short8 ah1 = *(const short8*)(Xhi + (size_t)(r0 + 16 + m) * 128 + koff);
        short8 al0 = *(const short8*)(Xlo + (size_t)(r0 + m) * 128 + koff);
        short8 al1 = *(const short8*)(Xlo + (size_t)(r0 + 16 + m) * 128 + koff);
#pragma unroll
        for (int c = 0; c < NT; ++c) {
            short8 bh = *(const short8*)(Wthi + (c * 16 + m) * 128 + koff);
            short8 bl = *(const short8*)(Wtlo + (c * 16 + m) * 128 + koff);
            acc[0][c] = __builtin_amdgcn_mfma_f32_16x16x32_bf16(ah0, bh, acc[0][c], 0, 0, 0);
            acc[1][c] = __builtin_amdgcn_mfma_f32_16x16x32_bf16(ah1, bh, acc[1][c], 0, 0, 0);
            acc[0][c] = __builtin_amdgcn_mfma_f32_16x16x32_bf16(ah0, bl, acc[0][c], 0, 0, 0);
            acc[1][c] = __builtin_amdgcn_mfma_f32_16x16x32_bf16(ah1, bl, acc[1][c], 0, 0, 0);
            acc[0][c] = __builtin_amdgcn_mfma_f32_16x16x32_bf16(al0, bh, acc[0][c], 0, 0, 0);
            acc[1][c] = __builtin_amdgcn_mfma_f32_16x16x32_bf16(al1, bh, acc[1][c], 0, 0, 0);
        }
    }

    // epilogue: C/D layout col=lane&15, row=q*4+reg  [verified m89/m91]
    const int rb0 = r0 + q * 4;
    const int rb1 = r0 + 16 + q * 4;
    f32x4 dv0 = *(const f32x4*)(dinv + rb0);
    f32x4 dv1 = *(const f32x4*)(dinv + rb1);
#pragma unroll
    for (int c = 0; c < NT; ++c) {
        const int col = c * 16 + m;
#pragma unroll
        for (int r = 0; r < 4; ++r) {
            int row = rb0 + r;
            if (row < N_NODES) Y[(size_t)row * N + col] = acc[0][c][r] * dv0[r];
            row = rb1 + r;
            if (row < N_NODES) Y[(size_t)row * N + col] = acc[1][c][r] * dv1[r];
        }
    }
}

// ---------- CSR aggregation, K=128, fused epilogue, writes split bf16 ----------
__global__ __launch_bounds__(256) void agg_relu(const int* __restrict__ rowp,
                                                const int* __restrict__ srcs,
                                                const float* __restrict__ Y,
                                                const float* __restrict__ dinv,
                                                const float* __restrict__ b,
                                                short* __restrict__ Hhi,
                                                short* __restrict__ Hlo) {
    int t = threadIdx.x;
    int lane = t & 63, w = t >> 6;
    int d = blockIdx.x * 4 + w;
    if (d >= N_NODES) return;
    const float2* Y2 = (const float2*)Y;
    float2 acc = Y2[(size_t)d * 64 + lane];  // self loop
    int e = rowp[d], end = rowp[d + 1];
    for (; e + 4 <= end; e += 4) {
        int s0 = srcs[e], s1 = srcs[e + 1], s2 = srcs[e + 2], s3 = srcs[e + 3];
        float2 a0 = Y2[(size_t)s0 * 64 + lane];
        float2 a1 = Y2[(size_t)s1 * 64 + lane];
        float2 a2 = Y2[(size_t)s2 * 64 + lane];
        float2 a3 = Y2[(size_t)s3 * 64 + lane];
        acc.x += (a0.x + a1.x) + (a2.x + a3.x);
        acc.y += (a0.y + a1.y) + (a2.y + a3.y);
    }
    for (; e < end; ++e) {
        float2 a = Y2[(size_t)srcs[e] * 64 + lane];
        acc.x += a.x;
        acc.y += a.y;
    }
    float s = dinv[d];
    float2 bb = ((const float2*)b)[lane];
    float vx = fmaxf(s * acc.x + bb.x, 0.f);
    float vy = fmaxf(s * acc.y + bb.y, 0.f);
    short hx = f2b(vx), hy = f2b(vy);
    short lx = f2b(vx - b2f(hx)), ly = f2b(vy - b2f(hy));
    ((ushort2*)Hhi)[(size_t)d * 64 + lane] =
        make_ushort2((unsigned short)hx, (unsigned short)hy);
    ((ushort2*)Hlo)[(size_t)d * 64 + lane] =
        make_ushort2((unsigned short)lx, (unsigned short)ly);
}

// ---------- CSR aggregation, K=64, fused log_softmax ----------
__global__ __launch_bounds__(256) void agg_lsm(const int* __restrict__ rowp,
                                               const int* __restrict__ srcs,
                                               const float* __restrict__ Y,
                                               const float* __restrict__ dinv,
                                               const float* __restrict__ b,
                                               float* __restrict__ out) {
    int t = threadIdx.x;
    int lane = t & 63, w = t >> 6;
    int d = blockIdx.x * 4 + w;
    if (d >= N_NODES) return;
    float acc = Y[(size_t)d * 64 + lane];  // self loop
    int e = rowp[d], end = rowp[d + 1];
    for (; e + 4 <= end; e += 4) {
        int s0 = srcs[e], s1 = srcs[e + 1], s2 = srcs[e + 2], s3 = srcs[e + 3];
        acc += (Y[(size_t)s0 * 64 + lane] + Y[(size_t)s1 * 64 + lane]) +
               (Y[(size_t)s2 * 64 + lane] + Y[(size_t)s3 * 64 + lane]);
    }
    for (; e < end; ++e) acc += Y[(size_t)srcs[e] * 64 + lane];
    float v = dinv[d] * acc + b[lane];
    float m = v;
#pragma unroll
    for (int o = 32; o; o >>= 1) m = fmaxf(m, __shfl_xor(m, o));
    float ex = __expf(v - m);
    float su = ex;
#pragma unroll
    for (int o = 32; o; o >>= 1) su += __shfl_xor(su, o);
    out[(size_t)d * 64 + lane] = v - m - logf(su);
}

extern "C" void kernel_launch(void* const* d_in, const int* in_sizes, int n_in,
                              void* d_out, int out_size, void* d_ws, size_t ws_size,
                              hipStream_t stream) {
    const float* x  = (const float*)d_in[0];
    const float* W1 = (const float*)d_in[1];
    const float* b1 = (const float*)d_in[2];
    const float* W2 = (const float*)d_in[3];
    const float* b2 = (const float*)d_in[4];
    const int* edge = (const int*)d_in[5];
    const int* src = edge;
    const int* dst = edge + N_EDGES;
    float* out = (float*)d_out;

    char* ws = (char*)d_ws;
    int*   cnt   = (int*)(ws + 0);          //   400,000
    int*   fill  = (int*)(ws + 400000);     //   400,000 (adjacent: one memset)
    float* dinv  = (float*)(ws + 800000);   //   400,384 (padded to MROWS)
    int*   rowp  = (int*)(ws + 1200384);    //   400,004
    int*   part  = (int*)(ws + 1600512);    //     1,564
    int*   srcs  = (int*)(ws + 1602560);    // 6,400,000
    short* xhi   = (short*)(ws + 8388608);  // 25,624,576  (MROWS*128*2)
    short* xlo   = (short*)(ws + 34013184); // 25,624,576
    short* w1hi  = (short*)(ws + 59637760); //    32,768
    short* w1lo  = (short*)(ws + 59670528); //    32,768
    short* w2hi  = (short*)(ws + 59703296); //    16,384
    short* w2lo  = (short*)(ws + 59719680); //    16,384
    float* y1    = (float*)(ws + 59736064); // 51,249,152  (MROWS*128*4) -> ends ~111 MB
    // reuse: xhi/xlo dead after gemm1 -> h1 split lives there; y1 dead after agg_relu -> y2
    short* h1hi  = xhi;
    short* h1lo  = xlo;
    float* y2    = y1;

    // ---- CSR build + dinv ----
    hipMemsetAsync(cnt, 0, 800000, stream);  // cnt + fill
    count_deg<<<(N_EDGES + 255) / 256, 256, 0, stream>>>(dst, cnt);
    make_dinv<<<(N_NODES + 255) / 256, 256, 0, stream>>>(cnt, dinv);
    scan_reduce<<<SCAN_B, 256, 0, stream>>>(cnt, part);
    scan_part<<<1, 512, 0, stream>>>(part);
    scan_final<<<SCAN_B, 256, 0, stream>>>(cnt, part, rowp);
    fill_csr<<<(N_EDGES + 255) / 256, 256, 0, stream>>>(src, dst, rowp, fill, srcs);

    // ---- weight + input conversion ----
    convert_wt<128><<<(128 * 128 + 255) / 256, 256, 0, stream>>>(W1, w1hi, w1lo);
    convert_wt<64><<<(64 * 128 + 255) / 256, 256, 0, stream>>>(W2, w2hi, w2lo);
    convert_split<<<(N_NODES * 32 + 255) / 256, 256, 0, stream>>>(x, xhi, xlo, N_NODES * 32);

    // ---- layer 1 ----
    gemm_mfma<128><<<MROWS / 128, 256, 0, stream>>>(xhi, xlo, w1hi, w1lo, dinv, y1);
    agg_relu<<<(N_NODES + 3) / 4, 256, 0, stream>>>(rowp, srcs, y1, dinv, b1, h1hi, h1lo);

    // ---- layer 2 ----
    gemm_mfma<64><<<MROWS / 128, 256, 0, stream>>>(h1hi, h1lo, w2hi, w2lo, dinv, y2);
    agg_lsm<<<(N_NODES + 3) / 4, 256, 0, stream>>>(rowp, srcs, y2, dinv, b2, out);
}

// Round 4
// 492.337 us; speedup vs baseline: 2.8354x; 1.0906x over previous
//
#include <hip/hip_runtime.h>
#include <math.h>

#define N_NODES 100000
#define N_EDGES 1600000
#define SCAN_B 391          // ceil(N_NODES/256)
#define MROWS 100096        // 782*128, padded row count for guard-free tiles

typedef __attribute__((ext_vector_type(8))) short short8;  // 8 bf16 = 4 VGPRs
typedef __attribute__((ext_vector_type(4))) float f32x4;

__device__ __forceinline__ short f2b(float f) {            // fp32 -> bf16 RNE
    unsigned u = __float_as_uint(f);
    unsigned r = (u + 0x7FFFu + ((u >> 16) & 1u)) >> 16;
    return (short)r;
}
__device__ __forceinline__ float b2f(short s) {
    return __uint_as_float(((unsigned)(unsigned short)s) << 16);
}
__device__ __forceinline__ float b2fu(unsigned short s) {
    return __uint_as_float(((unsigned)s) << 16);
}

// load 8 fp32, produce hi/lo bf16 split in-register
__device__ __forceinline__ void split8(const float* __restrict__ p,
                                       short8& h, short8& l) {
    float4 v0 = ((const float4*)p)[0];
    float4 v1 = ((const float4*)p)[1];
    float vv[8] = {v0.x, v0.y, v0.z, v0.w, v1.x, v1.y, v1.z, v1.w};
#pragma unroll
    for (int i = 0; i < 8; ++i) {
        short hh = f2b(vv[i]);
        h[i] = hh;
        l[i] = f2b(vv[i] - b2f(hh));
    }
}

// ---------- degree / dinv ----------
__global__ __launch_bounds__(256) void count_deg(const int* __restrict__ dst,
                                                 int* __restrict__ cnt) {
    int e = blockIdx.x * 256 + threadIdx.x;
    if (e < N_EDGES) atomicAdd(&cnt[dst[e]], 1);
}

__global__ __launch_bounds__(256) void make_dinv(const int* __restrict__ cnt,
                                                 float* __restrict__ dinv) {
    int i = blockIdx.x * 256 + threadIdx.x;
    if (i < N_NODES) dinv[i] = rsqrtf((float)(cnt[i] + 1));
}

// ---------- exclusive scan (3 kernels) ----------
__global__ __launch_bounds__(256) void scan_reduce(const int* __restrict__ cnt,
                                                   int* __restrict__ part) {
    __shared__ int s[256];
    int t = threadIdx.x, i = blockIdx.x * 256 + t;
    s[t] = (i < N_NODES) ? cnt[i] : 0;
    __syncthreads();
    for (int off = 128; off; off >>= 1) {
        if (t < off) s[t] += s[t + off];
        __syncthreads();
    }
    if (!t) part[blockIdx.x] = s[0];
}

__global__ __launch_bounds__(512) void scan_part(int* __restrict__ part) {
    __shared__ int s[512];
    int t = threadIdx.x;
    int v = (t < SCAN_B) ? part[t] : 0;
    s[t] = v;
    __syncthreads();
    for (int off = 1; off < 512; off <<= 1) {
        int u = (t >= off) ? s[t - off] : 0;
        __syncthreads();
        s[t] += u;
        __syncthreads();
    }
    if (t < SCAN_B) part[t] = s[t] - v;  // exclusive
}

__global__ __launch_bounds__(256) void scan_final(const int* __restrict__ cnt,
                                                  const int* __restrict__ part,
                                                  int* __restrict__ rowp) {
    __shared__ int s[256];
    int t = threadIdx.x, i = blockIdx.x * 256 + t;
    int v = (i < N_NODES) ? cnt[i] : 0;
    s[t] = v;
    __syncthreads();
    for (int off = 1; off < 256; off <<= 1) {
        int u = (t >= off) ? s[t - off] : 0;
        __syncthreads();
        s[t] += u;
        __syncthreads();
    }
    if (i < N_NODES) rowp[i] = part[blockIdx.x] + s[t] - v;  // exclusive
    if (i == 0) rowp[N_NODES] = N_EDGES;
}

// ---------- counting-sort fill: srcs grouped by dst ----------
__global__ __launch_bounds__(256) void fill_csr(const int* __restrict__ src,
                                                const int* __restrict__ dst,
                                                const int* __restrict__ rowp,
                                                int* __restrict__ fill,
                                                int* __restrict__ srcs) {
    int e = blockIdx.x * 256 + threadIdx.x;
    if (e < N_EDGES) {
        int d = dst[e];
        int p = rowp[d] + atomicAdd(&fill[d], 1);
        srcs[p] = src[e];
    }
}

// ---------- W [128][N] fp32 -> Wt [N][128] split bf16 ----------
template<int N>
__global__ __launch_bounds__(256) void convert_wt(const float* __restrict__ W,
                                                  short* __restrict__ Whi,
                                                  short* __restrict__ Wlo) {
    int id = blockIdx.x * 256 + threadIdx.x;
    if (id < N * 128) {
        int n = id >> 7, k = id & 127;
        float v = W[k * N + n];
        short h = f2b(v);
        Whi[id] = h;
        Wlo[id] = f2b(v - b2f(h));
    }
}

// ---------- layer-1 GEMM: Y1b = bf16((X @ W1) * dinv), in-register X split ----------
// X: [N_NODES][128] fp32; Wt: [128][128] bf16 hi/lo pre-transposed
__global__ __launch_bounds__(256) void gemm1_mfma(const float* __restrict__ X,
                                                  const short* __restrict__ Wthi,
                                                  const short* __restrict__ Wtlo,
                                                  const float* __restrict__ dinv,
                                                  short* __restrict__ Yb) {
    const int t = threadIdx.x;
    const int w = t >> 6, lane = t & 63;
    const int m = lane & 15, q = lane >> 4;
    const int r0 = blockIdx.x * 128 + w * 32;
    const int ra = min(r0 + m, N_NODES - 1);        // clamp: X has exactly N_NODES rows
    const int rb = min(r0 + 16 + m, N_NODES - 1);

    f32x4 acc[2][8];
#pragma unroll
    for (int i = 0; i < 2; ++i)
#pragma unroll
        for (int c = 0; c < 8; ++c) acc[i][c] = (f32x4)(0.f);

#pragma unroll
    for (int kk = 0; kk < 4; ++kk) {
        const int koff = kk * 32 + q * 8;
        short8 ah0, al0, ah1, al1;
        split8(X + (size_t)ra * 128 + koff, ah0, al0);
        split8(X + (size_t)rb * 128 + koff, ah1, al1);
#pragma unroll
        for (int c = 0; c < 8; ++c) {
            short8 bh = *(const short8*)(Wthi + (c * 16 + m) * 128 + koff);
            short8 bl = *(const short8*)(Wtlo + (c * 16 + m) * 128 + koff);
            acc[0][c] = __builtin_amdgcn_mfma_f32_16x16x32_bf16(ah0, bh, acc[0][c], 0, 0, 0);
            acc[1][c] = __builtin_amdgcn_mfma_f32_16x16x32_bf16(ah1, bh, acc[1][c], 0, 0, 0);
            acc[0][c] = __builtin_amdgcn_mfma_f32_16x16x32_bf16(ah0, bl, acc[0][c], 0, 0, 0);
            acc[1][c] = __builtin_amdgcn_mfma_f32_16x16x32_bf16(ah1, bl, acc[1][c], 0, 0, 0);
            acc[0][c] = __builtin_amdgcn_mfma_f32_16x16x32_bf16(al0, bh, acc[0][c], 0, 0, 0);
            acc[1][c] = __builtin_amdgcn_mfma_f32_16x16x32_bf16(al1, bh, acc[1][c], 0, 0, 0);
        }
    }

    // C/D layout: col=lane&15, row=q*4+reg  [verified m89/m91]
    const int rb0 = r0 + q * 4;
    const int rb1 = r0 + 16 + q * 4;
    f32x4 dv0 = *(const f32x4*)(dinv + rb0);
    f32x4 dv1 = *(const f32x4*)(dinv + rb1);
#pragma unroll
    for (int c = 0; c < 8; ++c) {
        const int col = c * 16 + m;
#pragma unroll
        for (int r = 0; r < 4; ++r) {
            int row = rb0 + r;
            if (row < N_NODES) Yb[(size_t)row * 128 + col] = f2b(acc[0][c][r] * dv0[r]);
            row = rb1 + r;
            if (row < N_NODES) Yb[(size_t)row * 128 + col] = f2b(acc[1][c][r] * dv1[r]);
        }
    }
}

// ---------- layer-2 GEMM: Y2b = bf16((H @ W2) * dinv), H plain bf16 ----------
// H: [MROWS][128] bf16; Wt: [64][128] bf16 hi/lo
__global__ __launch_bounds__(256) void gemm2_mfma(const short* __restrict__ H,
                                                  const short* __restrict__ Wthi,
                                                  const short* __restrict__ Wtlo,
                                                  const float* __restrict__ dinv,
                                                  short* __restrict__ Yb) {
    const int t = threadIdx.x;
    const int w = t >> 6, lane = t & 63;
    const int m = lane & 15, q = lane >> 4;
    const int r0 = blockIdx.x * 128 + w * 32;

    f32x4 acc[2][4];
#pragma unroll
    for (int i = 0; i < 2; ++i)
#pragma unroll
        for (int c = 0; c < 4; ++c) acc[i][c] = (f32x4)(0.f);

#pragma unroll
    for (int kk = 0; kk < 4; ++kk) {
        const int koff = kk * 32 + q * 8;
        short8 ah0 = *(const short8*)(H + (size_t)(r0 + m) * 128 + koff);
        short8 ah1 = *(const short8*)(H + (size_t)(r0 + 16 + m) * 128 + koff);
#pragma unroll
        for (int c = 0; c < 4; ++c) {
            short8 bh = *(const short8*)(Wthi + (c * 16 + m) * 128 + koff);
            short8 bl = *(const short8*)(Wtlo + (c * 16 + m) * 128 + koff);
            acc[0][c] = __builtin_amdgcn_mfma_f32_16x16x32_bf16(ah0, bh, acc[0][c], 0, 0, 0);
            acc[1][c] = __builtin_amdgcn_mfma_f32_16x16x32_bf16(ah1, bh, acc[1][c], 0, 0, 0);
            acc[0][c] = __builtin_amdgcn_mfma_f32_16x16x32_bf16(ah0, bl, acc[0][c], 0, 0, 0);
            acc[1][c] = __builtin_amdgcn_mfma_f32_16x16x32_bf16(ah1, bl, acc[1][c], 0, 0, 0);
        }
    }

    const int rb0 = r0 + q * 4;
    const int rb1 = r0 + 16 + q * 4;
    f32x4 dv0 = *(const f32x4*)(dinv + rb0);
    f32x4 dv1 = *(const f32x4*)(dinv + rb1);
#pragma unroll
    for (int c = 0; c < 4; ++c) {
        const int col = c * 16 + m;
#pragma unroll
        for (int r = 0; r < 4; ++r) {
            int row = rb0 + r;
            if (row < N_NODES) Yb[(size_t)row * 64 + col] = f2b(acc[0][c][r] * dv0[r]);
            row = rb1 + r;
            if (row < N_NODES) Yb[(size_t)row * 64 + col] = f2b(acc[1][c][r] * dv1[r]);
        }
    }
}

// ---------- CSR aggregation, K=128 bf16 in, fused epilogue, bf16 out ----------
__global__ __launch_bounds__(256) void agg_relu(const int* __restrict__ rowp,
                                                const int* __restrict__ srcs,
                                                const short* __restrict__ Yb,
                                                const float* __restrict__ dinv,
                                                const float* __restrict__ b,
                                                short* __restrict__ Hb) {
    int t = threadIdx.x;
    int lane = t & 63, w = t >> 6;
    int d = blockIdx.x * 4 + w;
    if (d >= N_NODES) return;
    const ushort2* Y2 = (const ushort2*)Yb;
    ushort2 u = Y2[(size_t)d * 64 + lane];  // self loop
    float accx = b2fu(u.x), accy = b2fu(u.y);
    int e = rowp[d], end = rowp[d + 1];
    for (; e + 4 <= end; e += 4) {
        int s0 = srcs[e], s1 = srcs[e + 1], s2 = srcs[e + 2], s3 = srcs[e + 3];
        ushort2 a0 = Y2[(size_t)s0 * 64 + lane];
        ushort2 a1 = Y2[(size_t)s1 * 64 + lane];
        ushort2 a2 = Y2[(size_t)s2 * 64 + lane];
        ushort2 a3 = Y2[(size_t)s3 * 64 + lane];
        accx += (b2fu(a0.x) + b2fu(a1.x)) + (b2fu(a2.x) + b2fu(a3.x));
        accy += (b2fu(a0.y) + b2fu(a1.y)) + (b2fu(a2.y) + b2fu(a3.y));
    }
    for (; e < end; ++e) {
        ushort2 a = Y2[(size_t)srcs[e] * 64 + lane];
        accx += b2fu(a.x);
        accy += b2fu(a.y);
    }
    float s = dinv[d];
    float2 bb = ((const float2*)b)[lane];
    float vx = fmaxf(s * accx + bb.x, 0.f);
    float vy = fmaxf(s * accy + bb.y, 0.f);
    ((ushort2*)Hb)[(size_t)d * 64 + lane] =
        make_ushort2((unsigned short)f2b(vx), (unsigned short)f2b(vy));
}

// ---------- CSR aggregation, K=64 bf16 in, fused log_softmax ----------
__global__ __launch_bounds__(256) void agg_lsm(const int* __restrict__ rowp,
                                               const int* __restrict__ srcs,
                                               const unsigned short* __restrict__ Yb,
                                               const float* __restrict__ dinv,
                                               const float* __restrict__ b,
                                               float* __restrict__ out) {
    int t = threadIdx.x;
    int lane = t & 63, w = t >> 6;
    int d = blockIdx.x * 4 + w;
    if (d >= N_NODES) return;
    float acc = b2fu(Yb[(size_t)d * 64 + lane]);  // self loop
    int e = rowp[d], end = rowp[d + 1];
    for (; e + 4 <= end; e += 4) {
        int s0 = srcs[e], s1 = srcs[e + 1], s2 = srcs[e + 2], s3 = srcs[e + 3];
        acc += (b2fu(Yb[(size_t)s0 * 64 + lane]) + b2fu(Yb[(size_t)s1 * 64 + lane])) +
               (b2fu(Yb[(size_t)s2 * 64 + lane]) + b2fu(Yb[(size_t)s3 * 64 + lane]));
    }
    for (; e < end; ++e) acc += b2fu(Yb[(size_t)srcs[e] * 64 + lane]);
    float v = dinv[d] * acc + b[lane];
    float m = v;
#pragma unroll
    for (int o = 32; o; o >>= 1) m = fmaxf(m, __shfl_xor(m, o));
    float ex = __expf(v - m);
    float su = ex;
#pragma unroll
    for (int o = 32; o; o >>= 1) su += __shfl_xor(su, o);
    out[(size_t)d * 64 + lane] = v - m - logf(su);
}

extern "C" void kernel_launch(void* const* d_in, const int* in_sizes, int n_in,
                              void* d_out, int out_size, void* d_ws, size_t ws_size,
                              hipStream_t stream) {
    const float* x  = (const float*)d_in[0];
    const float* W1 = (const float*)d_in[1];
    const float* b1 = (const float*)d_in[2];
    const float* W2 = (const float*)d_in[3];
    const float* b2 = (const float*)d_in[4];
    const int* edge = (const int*)d_in[5];
    const int* src = edge;
    const int* dst = edge + N_EDGES;
    float* out = (float*)d_out;

    char* ws = (char*)d_ws;
    int*   cnt   = (int*)(ws + 0);           //   400,000
    int*   fill  = (int*)(ws + 400000);      //   400,000 (adjacent: one memset)
    float* dinv  = (float*)(ws + 800000);    //   400,384 (padded to MROWS)
    int*   rowp  = (int*)(ws + 1200384);     //   400,004
    int*   part  = (int*)(ws + 1600512);     //     1,564
    int*   srcs  = (int*)(ws + 1602560);     // 6,400,000
    short* w1hi  = (short*)(ws + 8002560);   //    32,768
    short* w1lo  = (short*)(ws + 8035328);   //    32,768
    short* w2hi  = (short*)(ws + 8068096);   //    16,384
    short* w2lo  = (short*)(ws + 8084480);   //    16,384
    short* y1b   = (short*)(ws + 8388608);   // 25,624,576  (MROWS*128*2)
    short* h1b   = (short*)(ws + 34013184);  // 25,624,576
    short* y2b   = (short*)(ws + 59637760);  // 12,812,288  (MROWS*64*2) -> ends ~72.5 MB

    // ---- CSR build + dinv ----
    hipMemsetAsync(cnt, 0, 800000, stream);  // cnt + fill
    count_deg<<<(N_EDGES + 255) / 256, 256, 0, stream>>>(dst, cnt);
    make_dinv<<<(N_NODES + 255) / 256, 256, 0, stream>>>(cnt, dinv);
    scan_reduce<<<SCAN_B, 256, 0, stream>>>(cnt, part);
    scan_part<<<1, 512, 0, stream>>>(part);
    scan_final<<<SCAN_B, 256, 0, stream>>>(cnt, part, rowp);
    fill_csr<<<(N_EDGES + 255) / 256, 256, 0, stream>>>(src, dst, rowp, fill, srcs);

    // ---- weight conversion ----
    convert_wt<128><<<(128 * 128 + 255) / 256, 256, 0, stream>>>(W1, w1hi, w1lo);
    convert_wt<64><<<(64 * 128 + 255) / 256, 256, 0, stream>>>(W2, w2hi, w2lo);

    // ---- layer 1 ----
    gemm1_mfma<<<MROWS / 128, 256, 0, stream>>>(x, w1hi, w1lo, dinv, y1b);
    agg_relu<<<(N_NODES + 3) / 4, 256, 0, stream>>>(rowp, srcs, y1b, dinv, b1, h1b);

    // ---- layer 2 ----
    gemm2_mfma<<<MROWS / 128, 256, 0, stream>>>(h1b, w2hi, w2lo, dinv, y2b);
    agg_lsm<<<(N_NODES + 3) / 4, 256, 0, stream>>>(rowp, srcs, (const unsigned short*)y2b,
                                                   dinv, b2, out);
}

// Round 5
// 430.415 us; speedup vs baseline: 3.2433x; 1.1439x over previous
//
#include <hip/hip_runtime.h>
#include <math.h>

#define N_NODES 100000
#define N_EDGES 1600000
#define SCAN_B 391          // ceil(N_NODES/256)
#define MROWS 100096        // 782*128, padded row count for guard-free tiles
#define NB 391              // dst buckets (d>>8), 256 nodes each
#define CH 6400             // edges per bucket_scatter block; 250 blocks exactly

typedef __attribute__((ext_vector_type(8))) short short8;  // 8 bf16 = 4 VGPRs
typedef __attribute__((ext_vector_type(4))) float f32x4;

__device__ __forceinline__ short f2b(float f) {            // fp32 -> bf16 RNE
    unsigned u = __float_as_uint(f);
    unsigned r = (u + 0x7FFFu + ((u >> 16) & 1u)) >> 16;
    return (short)r;
}
__device__ __forceinline__ float b2f(short s) {
    return __uint_as_float(((unsigned)(unsigned short)s) << 16);
}
__device__ __forceinline__ float b2fu(unsigned short s) {
    return __uint_as_float(((unsigned)s) << 16);
}

// load 8 fp32, produce hi/lo bf16 split in-register
__device__ __forceinline__ void split8(const float* __restrict__ p,
                                       short8& h, short8& l) {
    float4 v0 = ((const float4*)p)[0];
    float4 v1 = ((const float4*)p)[1];
    float vv[8] = {v0.x, v0.y, v0.z, v0.w, v1.x, v1.y, v1.z, v1.w};
#pragma unroll
    for (int i = 0; i < 8; ++i) {
        short hh = f2b(vv[i]);
        h[i] = hh;
        l[i] = f2b(vv[i] - b2f(hh));
    }
}

// ---------- degree count + bucket histogram (fused) ----------
__global__ __launch_bounds__(256) void count_deg_bucket(const int* __restrict__ dst,
                                                        int* __restrict__ cnt,
                                                        int* __restrict__ bcnt) {
    __shared__ int h[NB];
    int t = threadIdx.x;
    for (int i = t; i < NB; i += 256) h[i] = 0;
    __syncthreads();
    for (int e = blockIdx.x * 256 + t; e < N_EDGES; e += gridDim.x * 256) {
        int d = dst[e];
        atomicAdd(&cnt[d], 1);
        atomicAdd(&h[d >> 8], 1);
    }
    __syncthreads();
    for (int i = t; i < NB; i += 256)
        if (h[i]) atomicAdd(&bcnt[i], h[i]);
}

// ---------- node-level exclusive scan (3 kernels); scan_reduce also emits dinv ----------
__global__ __launch_bounds__(256) void scan_reduce(const int* __restrict__ cnt,
                                                   int* __restrict__ part,
                                                   float* __restrict__ dinv) {
    __shared__ int s[256];
    int t = threadIdx.x, i = blockIdx.x * 256 + t;
    int v = (i < N_NODES) ? cnt[i] : 0;
    if (i < N_NODES) dinv[i] = rsqrtf((float)(v + 1));
    s[t] = v;
    __syncthreads();
    for (int off = 128; off; off >>= 1) {
        if (t < off) s[t] += s[t + off];
        __syncthreads();
    }
    if (!t) part[blockIdx.x] = s[0];
}

__global__ __launch_bounds__(512) void scan_part(int* __restrict__ part) {
    __shared__ int s[512];
    int t = threadIdx.x;
    int v = (t < SCAN_B) ? part[t] : 0;
    s[t] = v;
    __syncthreads();
    for (int off = 1; off < 512; off <<= 1) {
        int u = (t >= off) ? s[t - off] : 0;
        __syncthreads();
        s[t] += u;
        __syncthreads();
    }
    if (t < SCAN_B) part[t] = s[t] - v;  // exclusive
}

__global__ __launch_bounds__(256) void scan_final(const int* __restrict__ cnt,
                                                  const int* __restrict__ part,
                                                  int* __restrict__ rowp) {
    __shared__ int s[256];
    int t = threadIdx.x, i = blockIdx.x * 256 + t;
    int v = (i < N_NODES) ? cnt[i] : 0;
    s[t] = v;
    __syncthreads();
    for (int off = 1; off < 256; off <<= 1) {
        int u = (t >= off) ? s[t - off] : 0;
        __syncthreads();
        s[t] += u;
        __syncthreads();
    }
    if (i < N_NODES) rowp[i] = part[blockIdx.x] + s[t] - v;  // exclusive
    if (i == 0) rowp[N_NODES] = N_EDGES;
}

// ---------- bucket-level exclusive scan (one block) ----------
__global__ __launch_bounds__(512) void bucket_scan(const int* __restrict__ bcnt,
                                                   int* __restrict__ boffs,
                                                   int* __restrict__ bcur) {
    __shared__ int s[512];
    int t = threadIdx.x;
    int v = (t < NB) ? bcnt[t] : 0;
    s[t] = v;
    __syncthreads();
    for (int off = 1; off < 512; off <<= 1) {
        int u = (t >= off) ? s[t - off] : 0;
        __syncthreads();
        s[t] += u;
        __syncthreads();
    }
    if (t < NB) {
        int ex = s[t] - v;
        boffs[t] = ex;
        bcur[t] = ex;
    }
    if (t == 0) boffs[NB] = N_EDGES;
}

// ---------- scatter edges into bucket-grouped pair list (run-reserved writes) ----------
__global__ __launch_bounds__(256) void bucket_scatter(const int* __restrict__ src,
                                                      const int* __restrict__ dst,
                                                      int* __restrict__ bcur,
                                                      int2* __restrict__ pairs) {
    __shared__ int ls[CH];
    __shared__ int ld[CH];
    __shared__ int cnt[NB];
    __shared__ int lstart[NB];
    int t = threadIdx.x;
    int e0 = blockIdx.x * CH;
    int n = min(CH, N_EDGES - e0);
    for (int i = t; i < NB; i += 256) cnt[i] = 0;
    __syncthreads();
    for (int i = t; i < n; i += 256) {
        int s = src[e0 + i], d = dst[e0 + i];
        ls[i] = s;
        ld[i] = d;
        atomicAdd(&cnt[d >> 8], 1);
    }
    __syncthreads();
    for (int b = t; b < NB; b += 256) {
        int c = cnt[b];
        lstart[b] = c ? atomicAdd(&bcur[b], c) : 0;
        cnt[b] = 0;  // reuse as local cursor
    }
    __syncthreads();
    for (int i = t; i < n; i += 256) {
        int d = ld[i];
        int b = d >> 8;
        int lo = atomicAdd(&cnt[b], 1);
        pairs[lstart[b] + lo] = make_int2(ls[i], d);
    }
}

// ---------- bucket-local CSR fill: LDS fill counters, L2-resident scatter window ----------
__global__ __launch_bounds__(256) void csr_fill_bucket(const int2* __restrict__ pairs,
                                                       const int* __restrict__ boffs,
                                                       const int* __restrict__ rowp,
                                                       int* __restrict__ srcs) {
    __shared__ int lfill[256];
    __shared__ int lrp[256];
    int t = threadIdx.x;
    int b = blockIdx.x;
    int base = b << 8;
    lfill[t] = 0;
    lrp[t] = (base + t < N_NODES) ? rowp[base + t] : 0;
    __syncthreads();
    int lo_e = boffs[b], hi_e = boffs[b + 1];
    for (int i = lo_e + t; i < hi_e; i += 256) {
        int2 p = pairs[i];
        int li = p.y - base;
        int off = atomicAdd(&lfill[li], 1);
        srcs[lrp[li] + off] = p.x;
    }
}

// ---------- W1 [128][128] + W2 [128][64] fp32 -> Wt [N][128] split bf16 (merged) ----------
__global__ __launch_bounds__(256) void convert_w(const float* __restrict__ W1,
                                                 const float* __restrict__ W2,
                                                 short* __restrict__ w1hi,
                                                 short* __restrict__ w1lo,
                                                 short* __restrict__ w2hi,
                                                 short* __restrict__ w2lo) {
    int id = blockIdx.x * 256 + threadIdx.x;
    if (id < 128 * 128) {
        int n = id >> 7, k = id & 127;
        float v = W1[k * 128 + n];
        short h = f2b(v);
        w1hi[id] = h;
        w1lo[id] = f2b(v - b2f(h));
    } else if (id < 128 * 128 + 64 * 128) {
        int j = id - 128 * 128;
        int n = j >> 7, k = j & 127;
        float v = W2[k * 64 + n];
        short h = f2b(v);
        w2hi[j] = h;
        w2lo[j] = f2b(v - b2f(h));
    }
}

// ---------- layer-1 GEMM: Y1b = bf16((X @ W1) * dinv), in-register X split ----------
__global__ __launch_bounds__(256) void gemm1_mfma(const float* __restrict__ X,
                                                  const short* __restrict__ Wthi,
                                                  const short* __restrict__ Wtlo,
                                                  const float* __restrict__ dinv,
                                                  short* __restrict__ Yb) {
    const int t = threadIdx.x;
    const int w = t >> 6, lane = t & 63;
    const int m = lane & 15, q = lane >> 4;
    const int r0 = blockIdx.x * 128 + w * 32;
    const int ra = min(r0 + m, N_NODES - 1);        // clamp: X has exactly N_NODES rows
    const int rb = min(r0 + 16 + m, N_NODES - 1);

    f32x4 acc[2][8];
#pragma unroll
    for (int i = 0; i < 2; ++i)
#pragma unroll
        for (int c = 0; c < 8; ++c) acc[i][c] = (f32x4)(0.f);

#pragma unroll
    for (int kk = 0; kk < 4; ++kk) {
        const int koff = kk * 32 + q * 8;
        short8 ah0, al0, ah1, al1;
        split8(X + (size_t)ra * 128 + koff, ah0, al0);
        split8(X + (size_t)rb * 128 + koff, ah1, al1);
#pragma unroll
        for (int c = 0; c < 8; ++c) {
            short8 bh = *(const short8*)(Wthi + (c * 16 + m) * 128 + koff);
            short8 bl = *(const short8*)(Wtlo + (c * 16 + m) * 128 + koff);
            acc[0][c] = __builtin_amdgcn_mfma_f32_16x16x32_bf16(ah0, bh, acc[0][c], 0, 0, 0);
            acc[1][c] = __builtin_amdgcn_mfma_f32_16x16x32_bf16(ah1, bh, acc[1][c], 0, 0, 0);
            acc[0][c] = __builtin_amdgcn_mfma_f32_16x16x32_bf16(ah0, bl, acc[0][c], 0, 0, 0);
            acc[1][c] = __builtin_amdgcn_mfma_f32_16x16x32_bf16(ah1, bl, acc[1][c], 0, 0, 0);
            acc[0][c] = __builtin_amdgcn_mfma_f32_16x16x32_bf16(al0, bh, acc[0][c], 0, 0, 0);
            acc[1][c] = __builtin_amdgcn_mfma_f32_16x16x32_bf16(al1, bh, acc[1][c], 0, 0, 0);
        }
    }

    // C/D layout: col=lane&15, row=q*4+reg  [verified m89/m91]
    const int rb0 = r0 + q * 4;
    const int rb1 = r0 + 16 + q * 4;
    f32x4 dv0 = *(const f32x4*)(dinv + rb0);
    f32x4 dv1 = *(const f32x4*)(dinv + rb1);
#pragma unroll
    for (int c = 0; c < 8; ++c) {
        const int col = c * 16 + m;
#pragma unroll
        for (int r = 0; r < 4; ++r) {
            int row = rb0 + r;
            if (row < N_NODES) Yb[(size_t)row * 128 + col] = f2b(acc[0][c][r] * dv0[r]);
            row = rb1 + r;
            if (row < N_NODES) Yb[(size_t)row * 128 + col] = f2b(acc[1][c][r] * dv1[r]);
        }
    }
}

// ---------- layer-2 GEMM: Y2b = bf16((H @ W2) * dinv), H plain bf16 ----------
__global__ __launch_bounds__(256) void gemm2_mfma(const short* __restrict__ H,
                                                  const short* __restrict__ Wthi,
                                                  const short* __restrict__ Wtlo,
                                                  const float* __restrict__ dinv,
                                                  short* __restrict__ Yb) {
    const int t = threadIdx.x;
    const int w = t >> 6, lane = t & 63;
    const int m = lane & 15, q = lane >> 4;
    const int r0 = blockIdx.x * 128 + w * 32;

    f32x4 acc[2][4];
#pragma unroll
    for (int i = 0; i < 2; ++i)
#pragma unroll
        for (int c = 0; c < 4; ++c) acc[i][c] = (f32x4)(0.f);

#pragma unroll
    for (int kk = 0; kk < 4; ++kk) {
        const int koff = kk * 32 + q * 8;
        short8 ah0 = *(const short8*)(H + (size_t)(r0 + m) * 128 + koff);
        short8 ah1 = *(const short8*)(H + (size_t)(r0 + 16 + m) * 128 + koff);
#pragma unroll
        for (int c = 0; c < 4; ++c) {
            short8 bh = *(const short8*)(Wthi + (c * 16 + m) * 128 + koff);
            short8 bl = *(const short8*)(Wtlo + (c * 16 + m) * 128 + koff);
            acc[0][c] = __builtin_amdgcn_mfma_f32_16x16x32_bf16(ah0, bh, acc[0][c], 0, 0, 0);
            acc[1][c] = __builtin_amdgcn_mfma_f32_16x16x32_bf16(ah1, bh, acc[1][c], 0, 0, 0);
            acc[0][c] = __builtin_amdgcn_mfma_f32_16x16x32_bf16(ah0, bl, acc[0][c], 0, 0, 0);
            acc[1][c] = __builtin_amdgcn_mfma_f32_16x16x32_bf16(ah1, bl, acc[1][c], 0, 0, 0);
        }
    }

    const int rb0 = r0 + q * 4;
    const int rb1 = r0 + 16 + q * 4;
    f32x4 dv0 = *(const f32x4*)(dinv + rb0);
    f32x4 dv1 = *(const f32x4*)(dinv + rb1);
#pragma unroll
    for (int c = 0; c < 4; ++c) {
        const int col = c * 16 + m;
#pragma unroll
        for (int r = 0; r < 4; ++r) {
            int row = rb0 + r;
            if (row < N_NODES) Yb[(size_t)row * 64 + col] = f2b(acc[0][c][r] * dv0[r]);
            row = rb1 + r;
            if (row < N_NODES) Yb[(size_t)row * 64 + col] = f2b(acc[1][c][r] * dv1[r]);
        }
    }
}

// ---------- CSR aggregation, K=128 bf16 in, fused epilogue, bf16 out ----------
__global__ __launch_bounds__(256) void agg_relu(const int* __restrict__ rowp,
                                                const int* __restrict__ srcs,
                                                const short* __restrict__ Yb,
                                                const float* __restrict__ dinv,
                                                const float* __restrict__ b,
                                                short* __restrict__ Hb) {
    int t = threadIdx.x;
    int lane = t & 63, w = t >> 6;
    int d = blockIdx.x * 4 + w;
    if (d >= N_NODES) return;
    const ushort2* Y2 = (const ushort2*)Yb;
    ushort2 u = Y2[(size_t)d * 64 + lane];  // self loop
    float accx = b2fu(u.x), accy = b2fu(u.y);
    int e = rowp[d], end = rowp[d + 1];
    for (; e + 4 <= end; e += 4) {
        int s0 = srcs[e], s1 = srcs[e + 1], s2 = srcs[e + 2], s3 = srcs[e + 3];
        ushort2 a0 = Y2[(size_t)s0 * 64 + lane];
        ushort2 a1 = Y2[(size_t)s1 * 64 + lane];
        ushort2 a2 = Y2[(size_t)s2 * 64 + lane];
        ushort2 a3 = Y2[(size_t)s3 * 64 + lane];
        accx += (b2fu(a0.x) + b2fu(a1.x)) + (b2fu(a2.x) + b2fu(a3.x));
        accy += (b2fu(a0.y) + b2fu(a1.y)) + (b2fu(a2.y) + b2fu(a3.y));
    }
    for (; e < end; ++e) {
        ushort2 a = Y2[(size_t)srcs[e] * 64 + lane];
        accx += b2fu(a.x);
        accy += b2fu(a.y);
    }
    float s = dinv[d];
    float2 bb = ((const float2*)b)[lane];
    float vx = fmaxf(s * accx + bb.x, 0.f);
    float vy = fmaxf(s * accy + bb.y, 0.f);
    ((ushort2*)Hb)[(size_t)d * 64 + lane] =
        make_ushort2((unsigned short)f2b(vx), (unsigned short)f2b(vy));
}

// ---------- CSR aggregation, K=64 bf16 in, fused log_softmax ----------
__global__ __launch_bounds__(256) void agg_lsm(const int* __restrict__ rowp,
                                               const int* __restrict__ srcs,
                                               const unsigned short* __restrict__ Yb,
                                               const float* __restrict__ dinv,
                                               const float* __restrict__ b,
                                               float* __restrict__ out) {
    int t = threadIdx.x;
    int lane = t & 63, w = t >> 6;
    int d = blockIdx.x * 4 + w;
    if (d >= N_NODES) return;
    float acc = b2fu(Yb[(size_t)d * 64 + lane]);  // self loop
    int e = rowp[d], end = rowp[d + 1];
    for (; e + 4 <= end; e += 4) {
        int s0 = srcs[e], s1 = srcs[e + 1], s2 = srcs[e + 2], s3 = srcs[e + 3];
        acc += (b2fu(Yb[(size_t)s0 * 64 + lane]) + b2fu(Yb[(size_t)s1 * 64 + lane])) +
               (b2fu(Yb[(size_t)s2 * 64 + lane]) + b2fu(Yb[(size_t)s3 * 64 + lane]));
    }
    for (; e < end; ++e) acc += b2fu(Yb[(size_t)srcs[e] * 64 + lane]);
    float v = dinv[d] * acc + b[lane];
    float m = v;
#pragma unroll
    for (int o = 32; o; o >>= 1) m = fmaxf(m, __shfl_xor(m, o));
    float ex = __expf(v - m);
    float su = ex;
#pragma unroll
    for (int o = 32; o; o >>= 1) su += __shfl_xor(su, o);
    out[(size_t)d * 64 + lane] = v - m - logf(su);
}

extern "C" void kernel_launch(void* const* d_in, const int* in_sizes, int n_in,
                              void* d_out, int out_size, void* d_ws, size_t ws_size,
                              hipStream_t stream) {
    const float* x  = (const float*)d_in[0];
    const float* W1 = (const float*)d_in[1];
    const float* b1 = (const float*)d_in[2];
    const float* W2 = (const float*)d_in[3];
    const float* b2 = (const float*)d_in[4];
    const int* edge = (const int*)d_in[5];
    const int* src = edge;
    const int* dst = edge + N_EDGES;
    float* out = (float*)d_out;

    char* ws = (char*)d_ws;
    int*   cnt   = (int*)(ws + 0);           //   400,000
    int*   bcnt  = (int*)(ws + 400000);      //     1,564  (adjacent: one memset)
    float* dinv  = (float*)(ws + 801792);    //   400,384  (MROWS floats, 128-aligned)
    int*   rowp  = (int*)(ws + 1202176);     //   400,004
    int*   part  = (int*)(ws + 1602560);     //     1,564
    int*   boffs = (int*)(ws + 1604224);     //     1,568
    int*   bcur  = (int*)(ws + 1605792);     //     1,564
    int*   srcs  = (int*)(ws + 1607424);     // 6,400,000
    int2*  pairs = (int2*)(ws + 8007424);    // 12,800,000
    short* w1hi  = (short*)(ws + 20807424);  //    32,768
    short* w1lo  = (short*)(ws + 20840192);  //    32,768
    short* w2hi  = (short*)(ws + 20872960);  //    16,384
    short* w2lo  = (short*)(ws + 20889344);  //    16,384
    short* y1b   = (short*)(ws + 20905728);  // 25,624,576  (MROWS*128*2)
    short* h1b   = (short*)(ws + 46530304);  // 25,624,576
    short* y2b   = (short*)(ws + 72154880);  // 12,812,288  -> ends ~85 MB

    // ---- CSR build (two-level bucketed counting sort) + dinv ----
    hipMemsetAsync(cnt, 0, 401564, stream);  // cnt + bcnt
    count_deg_bucket<<<512, 256, 0, stream>>>(dst, cnt, bcnt);
    scan_reduce<<<SCAN_B, 256, 0, stream>>>(cnt, part, dinv);
    scan_part<<<1, 512, 0, stream>>>(part);
    scan_final<<<SCAN_B, 256, 0, stream>>>(cnt, part, rowp);
    bucket_scan<<<1, 512, 0, stream>>>(bcnt, boffs, bcur);
    bucket_scatter<<<(N_EDGES + CH - 1) / CH, 256, 0, stream>>>(src, dst, bcur, pairs);
    csr_fill_bucket<<<NB, 256, 0, stream>>>(pairs, boffs, rowp, srcs);

    // ---- weight conversion (merged) ----
    convert_w<<<(128 * 128 + 64 * 128 + 255) / 256, 256, 0, stream>>>(W1, W2, w1hi, w1lo,
                                                                      w2hi, w2lo);

    // ---- layer 1 ----
    gemm1_mfma<<<MROWS / 128, 256, 0, stream>>>(x, w1hi, w1lo, dinv, y1b);
    agg_relu<<<(N_NODES + 3) / 4, 256, 0, stream>>>(rowp, srcs, y1b, dinv, b1, h1b);

    // ---- layer 2 ----
    gemm2_mfma<<<MROWS / 128, 256, 0, stream>>>(h1b, w2hi, w2lo, dinv, y2b);
    agg_lsm<<<(N_NODES + 3) / 4, 256, 0, stream>>>(rowp, srcs, (const unsigned short*)y2b,
                                                   dinv, b2, out);
}

// Round 6
// 406.873 us; speedup vs baseline: 3.4309x; 1.0579x over previous
//
#include <hip/hip_runtime.h>
#include <math.h>

#define N_NODES 100000
#define N_EDGES 1600000
#define SCAN_B 391          // ceil(N_NODES/256) == bucket count (256 nodes/bucket)
#define NB 391
#define MROWS 100096        // 782*128, padded row count for guard-free tiles
#define CH 3200             // edges per bucket_scatter block -> 500 blocks

typedef __attribute__((ext_vector_type(8))) short short8;  // 8 bf16 = 4 VGPRs
typedef __attribute__((ext_vector_type(4))) float f32x4;

__device__ __forceinline__ short f2b(float f) {            // fp32 -> bf16 RNE
    unsigned u = __float_as_uint(f);
    unsigned r = (u + 0x7FFFu + ((u >> 16) & 1u)) >> 16;
    return (short)r;
}
__device__ __forceinline__ float b2f(short s) {
    return __uint_as_float(((unsigned)(unsigned short)s) << 16);
}
__device__ __forceinline__ float b2fu(unsigned short s) {
    return __uint_as_float(((unsigned)s) << 16);
}

// pack 8 fp32 -> 8 bf16 (RNE, no residual)
__device__ __forceinline__ short8 pack8(const float* __restrict__ p) {
    float4 v0 = ((const float4*)p)[0];
    float4 v1 = ((const float4*)p)[1];
    short8 h;
    h[0] = f2b(v0.x); h[1] = f2b(v0.y); h[2] = f2b(v0.z); h[3] = f2b(v0.w);
    h[4] = f2b(v1.x); h[5] = f2b(v1.y); h[6] = f2b(v1.z); h[7] = f2b(v1.w);
    return h;
}

// ---------- degree count ----------
__global__ __launch_bounds__(256) void count_deg(const int* __restrict__ dst,
                                                 int* __restrict__ cnt) {
    for (int e = blockIdx.x * 256 + threadIdx.x; e < N_EDGES; e += gridDim.x * 256)
        atomicAdd(&cnt[dst[e]], 1);
}

// ---------- node-level exclusive scan; scan_reduce also emits dinv ----------
// NOTE: block sums (part) double as bucket counts since buckets == scan blocks.
__global__ __launch_bounds__(256) void scan_reduce(const int* __restrict__ cnt,
                                                   int* __restrict__ part,
                                                   float* __restrict__ dinv) {
    __shared__ int s[256];
    int t = threadIdx.x, i = blockIdx.x * 256 + t;
    int v = (i < N_NODES) ? cnt[i] : 0;
    if (i < N_NODES) dinv[i] = rsqrtf((float)(v + 1));
    s[t] = v;
    __syncthreads();
    for (int off = 128; off; off >>= 1) {
        if (t < off) s[t] += s[t + off];
        __syncthreads();
    }
    if (!t) part[blockIdx.x] = s[0];
}

// exclusive-scan part in place; part becomes bucket offsets (boffs); emit bcur copy
__global__ __launch_bounds__(512) void scan_part(int* __restrict__ part,
                                                 int* __restrict__ bcur) {
    __shared__ int s[512];
    int t = threadIdx.x;
    int v = (t < SCAN_B) ? part[t] : 0;
    s[t] = v;
    __syncthreads();
    for (int off = 1; off < 512; off <<= 1) {
        int u = (t >= off) ? s[t - off] : 0;
        __syncthreads();
        s[t] += u;
        __syncthreads();
    }
    if (t < SCAN_B) {
        int ex = s[t] - v;
        part[t] = ex;
        bcur[t] = ex;
    }
    if (t == 0) part[SCAN_B] = N_EDGES;
}

__global__ __launch_bounds__(256) void scan_final(const int* __restrict__ cnt,
                                                  const int* __restrict__ part,
                                                  int* __restrict__ rowp) {
    __shared__ int s[256];
    int t = threadIdx.x, i = blockIdx.x * 256 + t;
    int v = (i < N_NODES) ? cnt[i] : 0;
    s[t] = v;
    __syncthreads();
    for (int off = 1; off < 256; off <<= 1) {
        int u = (t >= off) ? s[t - off] : 0;
        __syncthreads();
        s[t] += u;
        __syncthreads();
    }
    if (i < N_NODES) rowp[i] = part[blockIdx.x] + s[t] - v;  // exclusive
    if (i == 0) rowp[N_NODES] = N_EDGES;
}

// ---------- scatter edges into bucket-grouped packed list ----------
// packed word: (d&255)<<24 | src   (src < 2^24)
__global__ __launch_bounds__(256) void bucket_scatter(const int* __restrict__ src,
                                                      const int* __restrict__ dst,
                                                      int* __restrict__ bcur,
                                                      unsigned* __restrict__ pairs) {
    __shared__ unsigned lw[CH];
    __shared__ short lb[CH];
    __shared__ int cnt[NB];
    __shared__ int lstart[NB];
    int t = threadIdx.x;
    int e0 = blockIdx.x * CH;
    int n = min(CH, N_EDGES - e0);
    for (int i = t; i < NB; i += 256) cnt[i] = 0;
    __syncthreads();
    for (int i = t; i < n; i += 256) {
        int s = src[e0 + i], d = dst[e0 + i];
        lw[i] = ((unsigned)(d & 255) << 24) | (unsigned)s;
        int b = d >> 8;
        lb[i] = (short)b;
        atomicAdd(&cnt[b], 1);
    }
    __syncthreads();
    for (int b = t; b < NB; b += 256) {
        int c = cnt[b];
        lstart[b] = c ? atomicAdd(&bcur[b], c) : 0;
        cnt[b] = 0;  // reuse as local cursor
    }
    __syncthreads();
    for (int i = t; i < n; i += 256) {
        int b = lb[i];
        int lo = atomicAdd(&cnt[b], 1);
        pairs[lstart[b] + lo] = lw[i];
    }
}

// ---------- bucket-local CSR fill ----------
__global__ __launch_bounds__(256) void csr_fill_bucket(const unsigned* __restrict__ pairs,
                                                       const int* __restrict__ boffs,
                                                       const int* __restrict__ rowp,
                                                       int* __restrict__ srcs) {
    __shared__ int lfill[256];
    __shared__ int lrp[256];
    int t = threadIdx.x;
    int b = blockIdx.x;
    int base = b << 8;
    lfill[t] = 0;
    lrp[t] = (base + t < N_NODES) ? rowp[base + t] : 0;
    __syncthreads();
    int lo_e = boffs[b], hi_e = boffs[b + 1];
    for (int i = lo_e + t; i < hi_e; i += 256) {
        unsigned p = pairs[i];
        int li = p >> 24;
        int off = atomicAdd(&lfill[li], 1);
        srcs[lrp[li] + off] = (int)(p & 0xFFFFFFu);
    }
}

// ---------- W1 [128][128] + W2 [128][64] fp32 -> Wt [N][128] split bf16 ----------
__global__ __launch_bounds__(256) void convert_w(const float* __restrict__ W1,
                                                 const float* __restrict__ W2,
                                                 short* __restrict__ w1hi,
                                                 short* __restrict__ w1lo,
                                                 short* __restrict__ w2hi,
                                                 short* __restrict__ w2lo) {
    int id = blockIdx.x * 256 + threadIdx.x;
    if (id < 128 * 128) {
        int n = id >> 7, k = id & 127;
        float v = W1[k * 128 + n];
        short h = f2b(v);
        w1hi[id] = h;
        w1lo[id] = f2b(v - b2f(h));
    } else if (id < 128 * 128 + 64 * 128) {
        int j = id - 128 * 128;
        int n = j >> 7, k = j & 127;
        float v = W2[k * 64 + n];
        short h = f2b(v);
        w2hi[j] = h;
        w2lo[j] = f2b(v - b2f(h));
    }
}

// ---------- layer-1 GEMM: Y1b = bf16((X @ W1) * dinv); A=bf16(X), B split ----------
__global__ __launch_bounds__(256) void gemm1_mfma(const float* __restrict__ X,
                                                  const short* __restrict__ Wthi,
                                                  const short* __restrict__ Wtlo,
                                                  const float* __restrict__ dinv,
                                                  short* __restrict__ Yb) {
    const int t = threadIdx.x;
    const int w = t >> 6, lane = t & 63;
    const int m = lane & 15, q = lane >> 4;
    const int r0 = blockIdx.x * 128 + w * 32;
    const int ra = min(r0 + m, N_NODES - 1);        // clamp: X has exactly N_NODES rows
    const int rb = min(r0 + 16 + m, N_NODES - 1);

    f32x4 acc[2][8];
#pragma unroll
    for (int i = 0; i < 2; ++i)
#pragma unroll
        for (int c = 0; c < 8; ++c) acc[i][c] = (f32x4)(0.f);

#pragma unroll
    for (int kk = 0; kk < 4; ++kk) {
        const int koff = kk * 32 + q * 8;
        short8 ah0 = pack8(X + (size_t)ra * 128 + koff);
        short8 ah1 = pack8(X + (size_t)rb * 128 + koff);
#pragma unroll
        for (int c = 0; c < 8; ++c) {
            short8 bh = *(const short8*)(Wthi + (c * 16 + m) * 128 + koff);
            short8 bl = *(const short8*)(Wtlo + (c * 16 + m) * 128 + koff);
            acc[0][c] = __builtin_amdgcn_mfma_f32_16x16x32_bf16(ah0, bh, acc[0][c], 0, 0, 0);
            acc[1][c] = __builtin_amdgcn_mfma_f32_16x16x32_bf16(ah1, bh, acc[1][c], 0, 0, 0);
            acc[0][c] = __builtin_amdgcn_mfma_f32_16x16x32_bf16(ah0, bl, acc[0][c], 0, 0, 0);
            acc[1][c] = __builtin_amdgcn_mfma_f32_16x16x32_bf16(ah1, bl, acc[1][c], 0, 0, 0);
        }
    }

    // C/D layout: col=lane&15, row=q*4+reg  [verified m89/m91]
    const int rb0 = r0 + q * 4;
    const int rb1 = r0 + 16 + q * 4;
    f32x4 dv0 = *(const f32x4*)(dinv + rb0);
    f32x4 dv1 = *(const f32x4*)(dinv + rb1);
#pragma unroll
    for (int c = 0; c < 8; ++c) {
        const int col = c * 16 + m;
#pragma unroll
        for (int r = 0; r < 4; ++r) {
            int row = rb0 + r;
            if (row < N_NODES) Yb[(size_t)row * 128 + col] = f2b(acc[0][c][r] * dv0[r]);
            row = rb1 + r;
            if (row < N_NODES) Yb[(size_t)row * 128 + col] = f2b(acc[1][c][r] * dv1[r]);
        }
    }
}

// ---------- layer-2 GEMM: Y2b = bf16((H @ W2) * dinv), H plain bf16 ----------
__global__ __launch_bounds__(256) void gemm2_mfma(const short* __restrict__ H,
                                                  const short* __restrict__ Wthi,
                                                  const short* __restrict__ Wtlo,
                                                  const float* __restrict__ dinv,
                                                  short* __restrict__ Yb) {
    const int t = threadIdx.x;
    const int w = t >> 6, lane = t & 63;
    const int m = lane & 15, q = lane >> 4;
    const int r0 = blockIdx.x * 128 + w * 32;

    f32x4 acc[2][4];
#pragma unroll
    for (int i = 0; i < 2; ++i)
#pragma unroll
        for (int c = 0; c < 4; ++c) acc[i][c] = (f32x4)(0.f);

#pragma unroll
    for (int kk = 0; kk < 4; ++kk) {
        const int koff = kk * 32 + q * 8;
        short8 ah0 = *(const short8*)(H + (size_t)(r0 + m) * 128 + koff);
        short8 ah1 = *(const short8*)(H + (size_t)(r0 + 16 + m) * 128 + koff);
#pragma unroll
        for (int c = 0; c < 4; ++c) {
            short8 bh = *(const short8*)(Wthi + (c * 16 + m) * 128 + koff);
            short8 bl = *(const short8*)(Wtlo + (c * 16 + m) * 128 + koff);
            acc[0][c] = __builtin_amdgcn_mfma_f32_16x16x32_bf16(ah0, bh, acc[0][c], 0, 0, 0);
            acc[1][c] = __builtin_amdgcn_mfma_f32_16x16x32_bf16(ah1, bh, acc[1][c], 0, 0, 0);
            acc[0][c] = __builtin_amdgcn_mfma_f32_16x16x32_bf16(ah0, bl, acc[0][c], 0, 0, 0);
            acc[1][c] = __builtin_amdgcn_mfma_f32_16x16x32_bf16(ah1, bl, acc[1][c], 0, 0, 0);
        }
    }

    const int rb0 = r0 + q * 4;
    const int rb1 = r0 + 16 + q * 4;
    f32x4 dv0 = *(const f32x4*)(dinv + rb0);
    f32x4 dv1 = *(const f32x4*)(dinv + rb1);
#pragma unroll
    for (int c = 0; c < 4; ++c) {
        const int col = c * 16 + m;
#pragma unroll
        for (int r = 0; r < 4; ++r) {
            int row = rb0 + r;
            if (row < N_NODES) Yb[(size_t)row * 64 + col] = f2b(acc[0][c][r] * dv0[r]);
            row = rb1 + r;
            if (row < N_NODES) Yb[(size_t)row * 64 + col] = f2b(acc[1][c][r] * dv1[r]);
        }
    }
}

// ---------- CSR aggregation, K=128: half-wave per edge (2 edges/load) ----------
__global__ __launch_bounds__(256) void agg_relu(const int* __restrict__ rowp,
                                                const int* __restrict__ srcs,
                                                const short* __restrict__ Yb,
                                                const float* __restrict__ dinv,
                                                const float* __restrict__ b,
                                                short* __restrict__ Hb) {
    int t = threadIdx.x;
    int lane = t & 63, w = t >> 6;
    int half = lane >> 5, li = lane & 31;
    int d = blockIdx.x * 4 + w;
    if (d >= N_NODES) return;
    const ushort4* Y4 = (const ushort4*)Yb;  // row = 32 ushort4
    float4 acc = make_float4(0.f, 0.f, 0.f, 0.f);
    if (!half) {  // self loop into half 0
        ushort4 u = Y4[(size_t)d * 32 + li];
        acc.x = b2fu(u.x); acc.y = b2fu(u.y); acc.z = b2fu(u.z); acc.w = b2fu(u.w);
    }
    int e = rowp[d], end = rowp[d + 1];
    for (; e + 8 <= end; e += 8) {  // 8 edges: halves interleave, 4 loads in flight
        int s0 = srcs[e + half], s1 = srcs[e + 2 + half];
        int s2 = srcs[e + 4 + half], s3 = srcs[e + 6 + half];
        ushort4 a0 = Y4[(size_t)s0 * 32 + li];
        ushort4 a1 = Y4[(size_t)s1 * 32 + li];
        ushort4 a2 = Y4[(size_t)s2 * 32 + li];
        ushort4 a3 = Y4[(size_t)s3 * 32 + li];
        acc.x += (b2fu(a0.x) + b2fu(a1.x)) + (b2fu(a2.x) + b2fu(a3.x));
        acc.y += (b2fu(a0.y) + b2fu(a1.y)) + (b2fu(a2.y) + b2fu(a3.y));
        acc.z += (b2fu(a0.z) + b2fu(a1.z)) + (b2fu(a2.z) + b2fu(a3.z));
        acc.w += (b2fu(a0.w) + b2fu(a1.w)) + (b2fu(a2.w) + b2fu(a3.w));
    }
    for (; e < end; e += 2) {
        int idx = e + half;
        if (idx < end) {
            ushort4 a = Y4[(size_t)srcs[idx] * 32 + li];
            acc.x += b2fu(a.x); acc.y += b2fu(a.y);
            acc.z += b2fu(a.z); acc.w += b2fu(a.w);
        }
    }
    acc.x += __shfl_xor(acc.x, 32);
    acc.y += __shfl_xor(acc.y, 32);
    acc.z += __shfl_xor(acc.z, 32);
    acc.w += __shfl_xor(acc.w, 32);
    if (!half) {
        float sc = dinv[d];
        float4 bb = ((const float4*)b)[li];
        float v0 = fmaxf(sc * acc.x + bb.x, 0.f);
        float v1 = fmaxf(sc * acc.y + bb.y, 0.f);
        float v2 = fmaxf(sc * acc.z + bb.z, 0.f);
        float v3 = fmaxf(sc * acc.w + bb.w, 0.f);
        ushort4 o = make_ushort4((unsigned short)f2b(v0), (unsigned short)f2b(v1),
                                 (unsigned short)f2b(v2), (unsigned short)f2b(v3));
        ((ushort4*)Hb)[(size_t)d * 32 + li] = o;
    }
}

// ---------- CSR aggregation, K=64: half-wave per edge + fused log_softmax ----------
__global__ __launch_bounds__(256) void agg_lsm(const int* __restrict__ rowp,
                                               const int* __restrict__ srcs,
                                               const short* __restrict__ Yb,
                                               const float* __restrict__ dinv,
                                               const float* __restrict__ b,
                                               float* __restrict__ out) {
    int t = threadIdx.x;
    int lane = t & 63, w = t >> 6;
    int half = lane >> 5, li = lane & 31;
    int d = blockIdx.x * 4 + w;
    if (d >= N_NODES) return;
    const ushort2* Y2 = (const ushort2*)Yb;  // row = 32 ushort2
    float ax = 0.f, ay = 0.f;
    if (!half) {  // self loop
        ushort2 u = Y2[(size_t)d * 32 + li];
        ax = b2fu(u.x); ay = b2fu(u.y);
    }
    int e = rowp[d], end = rowp[d + 1];
    for (; e + 8 <= end; e += 8) {
        int s0 = srcs[e + half], s1 = srcs[e + 2 + half];
        int s2 = srcs[e + 4 + half], s3 = srcs[e + 6 + half];
        ushort2 a0 = Y2[(size_t)s0 * 32 + li];
        ushort2 a1 = Y2[(size_t)s1 * 32 + li];
        ushort2 a2 = Y2[(size_t)s2 * 32 + li];
        ushort2 a3 = Y2[(size_t)s3 * 32 + li];
        ax += (b2fu(a0.x) + b2fu(a1.x)) + (b2fu(a2.x) + b2fu(a3.x));
        ay += (b2fu(a0.y) + b2fu(a1.y)) + (b2fu(a2.y) + b2fu(a3.y));
    }
    for (; e < end; e += 2) {
        int idx = e + half;
        if (idx < end) {
            ushort2 a = Y2[(size_t)srcs[idx] * 32 + li];
            ax += b2fu(a.x); ay += b2fu(a.y);
        }
    }
    ax += __shfl_xor(ax, 32);
    ay += __shfl_xor(ay, 32);
    // all lanes now hold merged sums for features (2*li, 2*li+1)
    float sc = dinv[d];
    float2 bb = ((const float2*)b)[li];
    float vx = sc * ax + bb.x;
    float vy = sc * ay + bb.y;
    float m = fmaxf(vx, vy);
#pragma unroll
    for (int o = 16; o; o >>= 1) m = fmaxf(m, __shfl_xor(m, o));
    float su = __expf(vx - m) + __expf(vy - m);
#pragma unroll
    for (int o = 16; o; o >>= 1) su += __shfl_xor(su, o);
    float ls = logf(su);
    if (!half) {
        float2 o2 = make_float2(vx - m - ls, vy - m - ls);
        ((float2*)out)[(size_t)d * 32 + li] = o2;
    }
}

extern "C" void kernel_launch(void* const* d_in, const int* in_sizes, int n_in,
                              void* d_out, int out_size, void* d_ws, size_t ws_size,
                              hipStream_t stream) {
    const float* x  = (const float*)d_in[0];
    const float* W1 = (const float*)d_in[1];
    const float* b1 = (const float*)d_in[2];
    const float* W2 = (const float*)d_in[3];
    const float* b2 = (const float*)d_in[4];
    const int* edge = (const int*)d_in[5];
    const int* src = edge;
    const int* dst = edge + N_EDGES;
    float* out = (float*)d_out;

    char* ws = (char*)d_ws;
    int*      cnt   = (int*)(ws + 0);            //   400,000
    float*    dinv  = (float*)(ws + 401408);     //   400,384 (MROWS, 16B-aligned)
    int*      rowp  = (int*)(ws + 802816);       //   400,004
    int*      part  = (int*)(ws + 1204224);      //     1,568 (SCAN_B+1; == boffs)
    int*      bcur  = (int*)(ws + 1205888);      //     1,564
    int*      srcs  = (int*)(ws + 1207552);      // 6,400,000
    unsigned* pairs = (unsigned*)(ws + 7607552); // 6,400,000 (packed 4B)
    short*    w1hi  = (short*)(ws + 14007552);   //    32,768
    short*    w1lo  = (short*)(ws + 14040320);   //    32,768
    short*    w2hi  = (short*)(ws + 14073088);   //    16,384
    short*    w2lo  = (short*)(ws + 14089472);   //    16,384
    short*    y1b   = (short*)(ws + 14106624);   // 25,624,576 (MROWS*128*2)
    short*    h1b   = (short*)(ws + 39731200);   // 25,624,576
    short*    y2b   = (short*)(ws + 65355776);   // 12,812,288 -> ends ~78 MB

    // ---- CSR build (bucketed counting sort; buckets == scan blocks) + dinv ----
    hipMemsetAsync(cnt, 0, 400000, stream);
    count_deg<<<512, 256, 0, stream>>>(dst, cnt);
    scan_reduce<<<SCAN_B, 256, 0, stream>>>(cnt, part, dinv);
    scan_part<<<1, 512, 0, stream>>>(part, bcur);
    scan_final<<<SCAN_B, 256, 0, stream>>>(cnt, part, rowp);
    bucket_scatter<<<(N_EDGES + CH - 1) / CH, 256, 0, stream>>>(src, dst, bcur, pairs);
    csr_fill_bucket<<<NB, 256, 0, stream>>>(pairs, part, rowp, srcs);

    // ---- weight conversion ----
    convert_w<<<(128 * 128 + 64 * 128 + 255) / 256, 256, 0, stream>>>(W1, W2, w1hi, w1lo,
                                                                      w2hi, w2lo);

    // ---- layer 1 ----
    gemm1_mfma<<<MROWS / 128, 256, 0, stream>>>(x, w1hi, w1lo, dinv, y1b);
    agg_relu<<<(N_NODES + 3) / 4, 256, 0, stream>>>(rowp, srcs, y1b, dinv, b1, h1b);

    // ---- layer 2 ----
    gemm2_mfma<<<MROWS / 128, 256, 0, stream>>>(h1b, w2hi, w2lo, dinv, y2b);
    agg_lsm<<<(N_NODES + 3) / 4, 256, 0, stream>>>(rowp, srcs, y2b, dinv, b2, out);
}

// Round 7
// 393.898 us; speedup vs baseline: 3.5440x; 1.0329x over previous
//
#include <hip/hip_runtime.h>
#include <math.h>

#define N_NODES 100000
#define N_EDGES 1600000
#define SCAN_B 391          // ceil(N_NODES/256) == bucket count (256 nodes/bucket)
#define NB 391
#define MROWS 100096        // 782*128, padded row count for guard-free tiles
#define CH 3200             // edges per bucket_scatter block -> 500 blocks

typedef __attribute__((ext_vector_type(8))) short short8;  // 8 bf16 = 4 VGPRs
typedef __attribute__((ext_vector_type(4))) float f32x4;
typedef __attribute__((ext_vector_type(2))) __bf16 bf16x2; // v_pk_add_bf16 operand

union BU { unsigned u; bf16x2 b; };
__device__ __forceinline__ bf16x2 u2b(unsigned u) { BU x; x.u = u; return x.b; }
__device__ __forceinline__ unsigned b2u(bf16x2 b) { BU x; x.b = b; return x.u; }

__device__ __forceinline__ short f2b(float f) {            // fp32 -> bf16 RNE
    unsigned u = __float_as_uint(f);
    unsigned r = (u + 0x7FFFu + ((u >> 16) & 1u)) >> 16;
    return (short)r;
}
__device__ __forceinline__ float b2f(short s) {
    return __uint_as_float(((unsigned)(unsigned short)s) << 16);
}
__device__ __forceinline__ unsigned pk2(float a, float b) {
    return (unsigned)(unsigned short)f2b(a) | ((unsigned)(unsigned short)f2b(b) << 16);
}

// pack 8 fp32 -> 8 bf16 (RNE)
__device__ __forceinline__ short8 pack8(const float* __restrict__ p) {
    float4 v0 = ((const float4*)p)[0];
    float4 v1 = ((const float4*)p)[1];
    short8 h;
    h[0] = f2b(v0.x); h[1] = f2b(v0.y); h[2] = f2b(v0.z); h[3] = f2b(v0.w);
    h[4] = f2b(v1.x); h[5] = f2b(v1.y); h[6] = f2b(v1.z); h[7] = f2b(v1.w);
    return h;
}

// ---------- degree count ----------
__global__ __launch_bounds__(256) void count_deg(const int* __restrict__ dst,
                                                 int* __restrict__ cnt) {
    for (int e = blockIdx.x * 256 + threadIdx.x; e < N_EDGES; e += gridDim.x * 256)
        atomicAdd(&cnt[dst[e]], 1);
}

// ---------- node-level exclusive scan; scan_reduce also emits dinv ----------
__global__ __launch_bounds__(256) void scan_reduce(const int* __restrict__ cnt,
                                                   int* __restrict__ part,
                                                   float* __restrict__ dinv) {
    __shared__ int s[256];
    int t = threadIdx.x, i = blockIdx.x * 256 + t;
    int v = (i < N_NODES) ? cnt[i] : 0;
    if (i < N_NODES) dinv[i] = rsqrtf((float)(v + 1));
    s[t] = v;
    __syncthreads();
    for (int off = 128; off; off >>= 1) {
        if (t < off) s[t] += s[t + off];
        __syncthreads();
    }
    if (!t) part[blockIdx.x] = s[0];
}

// exclusive-scan part in place; part becomes bucket offsets (boffs); emit bcur copy
__global__ __launch_bounds__(512) void scan_part(int* __restrict__ part,
                                                 int* __restrict__ bcur) {
    __shared__ int s[512];
    int t = threadIdx.x;
    int v = (t < SCAN_B) ? part[t] : 0;
    s[t] = v;
    __syncthreads();
    for (int off = 1; off < 512; off <<= 1) {
        int u = (t >= off) ? s[t - off] : 0;
        __syncthreads();
        s[t] += u;
        __syncthreads();
    }
    if (t < SCAN_B) {
        int ex = s[t] - v;
        part[t] = ex;
        bcur[t] = ex;
    }
    if (t == 0) part[SCAN_B] = N_EDGES;
}

__global__ __launch_bounds__(256) void scan_final(const int* __restrict__ cnt,
                                                  const int* __restrict__ part,
                                                  int* __restrict__ rowp) {
    __shared__ int s[256];
    int t = threadIdx.x, i = blockIdx.x * 256 + t;
    int v = (i < N_NODES) ? cnt[i] : 0;
    s[t] = v;
    __syncthreads();
    for (int off = 1; off < 256; off <<= 1) {
        int u = (t >= off) ? s[t - off] : 0;
        __syncthreads();
        s[t] += u;
        __syncthreads();
    }
    if (i < N_NODES) rowp[i] = part[blockIdx.x] + s[t] - v;  // exclusive
    if (i == 0) rowp[N_NODES] = N_EDGES;
}

// ---------- scatter edges into bucket-grouped packed list ----------
// packed word: (d&255)<<24 | src   (src < 2^24)
__global__ __launch_bounds__(256) void bucket_scatter(const int* __restrict__ src,
                                                      const int* __restrict__ dst,
                                                      int* __restrict__ bcur,
                                                      unsigned* __restrict__ pairs) {
    __shared__ unsigned lw[CH];
    __shared__ short lb[CH];
    __shared__ int cnt[NB];
    __shared__ int lstart[NB];
    int t = threadIdx.x;
    int e0 = blockIdx.x * CH;
    int n = min(CH, N_EDGES - e0);
    for (int i = t; i < NB; i += 256) cnt[i] = 0;
    __syncthreads();
    for (int i = t; i < n; i += 256) {
        int s = src[e0 + i], d = dst[e0 + i];
        lw[i] = ((unsigned)(d & 255) << 24) | (unsigned)s;
        int b = d >> 8;
        lb[i] = (short)b;
        atomicAdd(&cnt[b], 1);
    }
    __syncthreads();
    for (int b = t; b < NB; b += 256) {
        int c = cnt[b];
        lstart[b] = c ? atomicAdd(&bcur[b], c) : 0;
        cnt[b] = 0;  // reuse as local cursor
    }
    __syncthreads();
    for (int i = t; i < n; i += 256) {
        int b = lb[i];
        int lo = atomicAdd(&cnt[b], 1);
        pairs[lstart[b] + lo] = lw[i];
    }
}

// ---------- bucket-local CSR fill ----------
__global__ __launch_bounds__(256) void csr_fill_bucket(const unsigned* __restrict__ pairs,
                                                       const int* __restrict__ boffs,
                                                       const int* __restrict__ rowp,
                                                       int* __restrict__ srcs) {
    __shared__ int lfill[256];
    __shared__ int lrp[256];
    int t = threadIdx.x;
    int b = blockIdx.x;
    int base = b << 8;
    lfill[t] = 0;
    lrp[t] = (base + t < N_NODES) ? rowp[base + t] : 0;
    __syncthreads();
    int lo_e = boffs[b], hi_e = boffs[b + 1];
    for (int i = lo_e + t; i < hi_e; i += 256) {
        unsigned p = pairs[i];
        int li = p >> 24;
        int off = atomicAdd(&lfill[li], 1);
        srcs[lrp[li] + off] = (int)(p & 0xFFFFFFu);
    }
}

// ---------- W1 [128][128] + W2 [128][64] fp32 -> Wt [N][128] split bf16 ----------
__global__ __launch_bounds__(256) void convert_w(const float* __restrict__ W1,
                                                 const float* __restrict__ W2,
                                                 short* __restrict__ w1hi,
                                                 short* __restrict__ w1lo,
                                                 short* __restrict__ w2hi,
                                                 short* __restrict__ w2lo) {
    int id = blockIdx.x * 256 + threadIdx.x;
    if (id < 128 * 128) {
        int n = id >> 7, k = id & 127;
        float v = W1[k * 128 + n];
        short h = f2b(v);
        w1hi[id] = h;
        w1lo[id] = f2b(v - b2f(h));
    } else if (id < 128 * 128 + 64 * 128) {
        int j = id - 128 * 128;
        int n = j >> 7, k = j & 127;
        float v = W2[k * 64 + n];
        short h = f2b(v);
        w2hi[j] = h;
        w2lo[j] = f2b(v - b2f(h));
    }
}

// ---------- layer-1 GEMM: Y1b = bf16((X @ W1) * dinv); A=bf16(X), B split ----------
__global__ __launch_bounds__(256) void gemm1_mfma(const float* __restrict__ X,
                                                  const short* __restrict__ Wthi,
                                                  const short* __restrict__ Wtlo,
                                                  const float* __restrict__ dinv,
                                                  short* __restrict__ Yb) {
    const int t = threadIdx.x;
    const int w = t >> 6, lane = t & 63;
    const int m = lane & 15, q = lane >> 4;
    const int r0 = blockIdx.x * 128 + w * 32;
    const int ra = min(r0 + m, N_NODES - 1);
    const int rb = min(r0 + 16 + m, N_NODES - 1);

    f32x4 acc[2][8];
#pragma unroll
    for (int i = 0; i < 2; ++i)
#pragma unroll
        for (int c = 0; c < 8; ++c) acc[i][c] = (f32x4)(0.f);

#pragma unroll
    for (int kk = 0; kk < 4; ++kk) {
        const int koff = kk * 32 + q * 8;
        short8 ah0 = pack8(X + (size_t)ra * 128 + koff);
        short8 ah1 = pack8(X + (size_t)rb * 128 + koff);
#pragma unroll
        for (int c = 0; c < 8; ++c) {
            short8 bh = *(const short8*)(Wthi + (c * 16 + m) * 128 + koff);
            short8 bl = *(const short8*)(Wtlo + (c * 16 + m) * 128 + koff);
            acc[0][c] = __builtin_amdgcn_mfma_f32_16x16x32_bf16(ah0, bh, acc[0][c], 0, 0, 0);
            acc[1][c] = __builtin_amdgcn_mfma_f32_16x16x32_bf16(ah1, bh, acc[1][c], 0, 0, 0);
            acc[0][c] = __builtin_amdgcn_mfma_f32_16x16x32_bf16(ah0, bl, acc[0][c], 0, 0, 0);
            acc[1][c] = __builtin_amdgcn_mfma_f32_16x16x32_bf16(ah1, bl, acc[1][c], 0, 0, 0);
        }
    }

    const int rb0 = r0 + q * 4;
    const int rb1 = r0 + 16 + q * 4;
    f32x4 dv0 = *(const f32x4*)(dinv + rb0);
    f32x4 dv1 = *(const f32x4*)(dinv + rb1);
#pragma unroll
    for (int c = 0; c < 8; ++c) {
        const int col = c * 16 + m;
#pragma unroll
        for (int r = 0; r < 4; ++r) {
            int row = rb0 + r;
            if (row < N_NODES) Yb[(size_t)row * 128 + col] = f2b(acc[0][c][r] * dv0[r]);
            row = rb1 + r;
            if (row < N_NODES) Yb[(size_t)row * 128 + col] = f2b(acc[1][c][r] * dv1[r]);
        }
    }
}

// ---------- layer-2 GEMM: Y2b = bf16((H @ W2) * dinv), H plain bf16 ----------
__global__ __launch_bounds__(256) void gemm2_mfma(const short* __restrict__ H,
                                                  const short* __restrict__ Wthi,
                                                  const short* __restrict__ Wtlo,
                                                  const float* __restrict__ dinv,
                                                  short* __restrict__ Yb) {
    const int t = threadIdx.x;
    const int w = t >> 6, lane = t & 63;
    const int m = lane & 15, q = lane >> 4;
    const int r0 = blockIdx.x * 128 + w * 32;

    f32x4 acc[2][4];
#pragma unroll
    for (int i = 0; i < 2; ++i)
#pragma unroll
        for (int c = 0; c < 4; ++c) acc[i][c] = (f32x4)(0.f);

#pragma unroll
    for (int kk = 0; kk < 4; ++kk) {
        const int koff = kk * 32 + q * 8;
        short8 ah0 = *(const short8*)(H + (size_t)(r0 + m) * 128 + koff);
        short8 ah1 = *(const short8*)(H + (size_t)(r0 + 16 + m) * 128 + koff);
#pragma unroll
        for (int c = 0; c < 4; ++c) {
            short8 bh = *(const short8*)(Wthi + (c * 16 + m) * 128 + koff);
            short8 bl = *(const short8*)(Wtlo + (c * 16 + m) * 128 + koff);
            acc[0][c] = __builtin_amdgcn_mfma_f32_16x16x32_bf16(ah0, bh, acc[0][c], 0, 0, 0);
            acc[1][c] = __builtin_amdgcn_mfma_f32_16x16x32_bf16(ah1, bh, acc[1][c], 0, 0, 0);
            acc[0][c] = __builtin_amdgcn_mfma_f32_16x16x32_bf16(ah0, bl, acc[0][c], 0, 0, 0);
            acc[1][c] = __builtin_amdgcn_mfma_f32_16x16x32_bf16(ah1, bl, acc[1][c], 0, 0, 0);
        }
    }

    const int rb0 = r0 + q * 4;
    const int rb1 = r0 + 16 + q * 4;
    f32x4 dv0 = *(const f32x4*)(dinv + rb0);
    f32x4 dv1 = *(const f32x4*)(dinv + rb1);
#pragma unroll
    for (int c = 0; c < 4; ++c) {
        const int col = c * 16 + m;
#pragma unroll
        for (int r = 0; r < 4; ++r) {
            int row = rb0 + r;
            if (row < N_NODES) Yb[(size_t)row * 64 + col] = f2b(acc[0][c][r] * dv0[r]);
            row = rb1 + r;
            if (row < N_NODES) Yb[(size_t)row * 64 + col] = f2b(acc[1][c][r] * dv1[r]);
        }
    }
}

// ---------- CSR aggregation, K=128: quarter-wave/edge, packed-bf16 accumulate ----------
__global__ __launch_bounds__(256) void agg_relu(const int* __restrict__ rowp,
                                                const int* __restrict__ srcs,
                                                const short* __restrict__ Yb,
                                                const float* __restrict__ dinv,
                                                const float* __restrict__ b,
                                                short* __restrict__ Hb) {
    int t = threadIdx.x;
    int lane = t & 63, w = t >> 6;
    int qi = lane >> 4, li = lane & 15;      // 4 quarter-groups of 16 lanes
    int d = blockIdx.x * 4 + w;
    if (d >= N_NODES) return;
    const uint4* Y4 = (const uint4*)Yb;      // row = 16 uint4 (128 bf16)
    bf16x2 a0 = u2b(0), a1 = u2b(0), a2 = u2b(0), a3 = u2b(0);
    if (qi == 0) {                            // self loop into group 0
        uint4 u = Y4[(size_t)d * 16 + li];
        a0 = u2b(u.x); a1 = u2b(u.y); a2 = u2b(u.z); a3 = u2b(u.w);
    }
    int e = rowp[d], end = rowp[d + 1];
    for (; e + 8 <= end; e += 8) {            // 8 edges: 2 loads in flight
        int s0 = srcs[e + qi], s1 = srcs[e + 4 + qi];
        uint4 u0 = Y4[(size_t)s0 * 16 + li];
        uint4 u1 = Y4[(size_t)s1 * 16 + li];
        a0 += u2b(u0.x) + u2b(u1.x);
        a1 += u2b(u0.y) + u2b(u1.y);
        a2 += u2b(u0.z) + u2b(u1.z);
        a3 += u2b(u0.w) + u2b(u1.w);
    }
    for (; e < end; e += 4) {                 // masked remainder, 4 edges/step
        int idx = e + qi;
        int s = srcs[(idx < end) ? idx : e];
        uint4 u = Y4[(size_t)s * 16 + li];
        if (idx < end) {
            a0 += u2b(u.x); a1 += u2b(u.y); a2 += u2b(u.z); a3 += u2b(u.w);
        }
    }
    // merge quarter-groups
    a0 += u2b(__shfl_xor((int)b2u(a0), 16)); a0 += u2b(__shfl_xor((int)b2u(a0), 32));
    a1 += u2b(__shfl_xor((int)b2u(a1), 16)); a1 += u2b(__shfl_xor((int)b2u(a1), 32));
    a2 += u2b(__shfl_xor((int)b2u(a2), 16)); a2 += u2b(__shfl_xor((int)b2u(a2), 32));
    a3 += u2b(__shfl_xor((int)b2u(a3), 16)); a3 += u2b(__shfl_xor((int)b2u(a3), 32));
    if (qi == 0) {                            // epilogue: feats 8*li .. 8*li+7
        float sc = dinv[d];
        float4 bb0 = ((const float4*)b)[2 * li];
        float4 bb1 = ((const float4*)b)[2 * li + 1];
        unsigned u0 = b2u(a0), u1 = b2u(a1), u2 = b2u(a2), u3 = b2u(a3);
        float v0 = fmaxf(sc * __uint_as_float(u0 << 16) + bb0.x, 0.f);
        float v1 = fmaxf(sc * __uint_as_float(u0 & 0xFFFF0000u) + bb0.y, 0.f);
        float v2 = fmaxf(sc * __uint_as_float(u1 << 16) + bb0.z, 0.f);
        float v3 = fmaxf(sc * __uint_as_float(u1 & 0xFFFF0000u) + bb0.w, 0.f);
        float v4 = fmaxf(sc * __uint_as_float(u2 << 16) + bb1.x, 0.f);
        float v5 = fmaxf(sc * __uint_as_float(u2 & 0xFFFF0000u) + bb1.y, 0.f);
        float v6 = fmaxf(sc * __uint_as_float(u3 << 16) + bb1.z, 0.f);
        float v7 = fmaxf(sc * __uint_as_float(u3 & 0xFFFF0000u) + bb1.w, 0.f);
        uint4 o = make_uint4(pk2(v0, v1), pk2(v2, v3), pk2(v4, v5), pk2(v6, v7));
        ((uint4*)Hb)[(size_t)d * 16 + li] = o;
    }
}

// ---------- CSR aggregation, K=64: eighth-wave/edge + fused log_softmax ----------
__global__ __launch_bounds__(256) void agg_lsm(const int* __restrict__ rowp,
                                               const int* __restrict__ srcs,
                                               const short* __restrict__ Yb,
                                               const float* __restrict__ dinv,
                                               const float* __restrict__ b,
                                               float* __restrict__ out) {
    int t = threadIdx.x;
    int lane = t & 63, w = t >> 6;
    int gi = lane >> 3, li = lane & 7;        // 8 octet-groups of 8 lanes
    int d = blockIdx.x * 4 + w;
    if (d >= N_NODES) return;
    const uint4* Y4 = (const uint4*)Yb;       // row = 8 uint4 (64 bf16)
    bf16x2 a0 = u2b(0), a1 = u2b(0), a2 = u2b(0), a3 = u2b(0);
    if (gi == 0) {                             // self loop
        uint4 u = Y4[(size_t)d * 8 + li];
        a0 = u2b(u.x); a1 = u2b(u.y); a2 = u2b(u.z); a3 = u2b(u.w);
    }
    int e = rowp[d], end = rowp[d + 1];
    for (; e + 16 <= end; e += 16) {           // 16 edges: 2 loads in flight
        int s0 = srcs[e + gi], s1 = srcs[e + 8 + gi];
        uint4 u0 = Y4[(size_t)s0 * 8 + li];
        uint4 u1 = Y4[(size_t)s1 * 8 + li];
        a0 += u2b(u0.x) + u2b(u1.x);
        a1 += u2b(u0.y) + u2b(u1.y);
        a2 += u2b(u0.z) + u2b(u1.z);
        a3 += u2b(u0.w) + u2b(u1.w);
    }
    for (; e < end; e += 8) {                  // masked remainder, 8 edges/step
        int idx = e + gi;
        int s = srcs[(idx < end) ? idx : e];
        uint4 u = Y4[(size_t)s * 8 + li];
        if (idx < end) {
            a0 += u2b(u.x); a1 += u2b(u.y); a2 += u2b(u.z); a3 += u2b(u.w);
        }
    }
    // merge octet-groups (levels 8, 16, 32) -> all lanes hold totals
#pragma unroll
    for (int off = 8; off <= 32; off <<= 1) {
        a0 += u2b(__shfl_xor((int)b2u(a0), off));
        a1 += u2b(__shfl_xor((int)b2u(a1), off));
        a2 += u2b(__shfl_xor((int)b2u(a2), off));
        a3 += u2b(__shfl_xor((int)b2u(a3), off));
    }
    // epilogue: lane li holds feats 8*li .. 8*li+7 (identical in every octet)
    float sc = dinv[d];
    float4 bb0 = ((const float4*)b)[2 * li];
    float4 bb1 = ((const float4*)b)[2 * li + 1];
    unsigned u0 = b2u(a0), u1 = b2u(a1), u2 = b2u(a2), u3 = b2u(a3);
    float v0 = sc * __uint_as_float(u0 << 16) + bb0.x;
    float v1 = sc * __uint_as_float(u0 & 0xFFFF0000u) + bb0.y;
    float v2 = sc * __uint_as_float(u1 << 16) + bb0.z;
    float v3 = sc * __uint_as_float(u1 & 0xFFFF0000u) + bb0.w;
    float v4 = sc * __uint_as_float(u2 << 16) + bb1.x;
    float v5 = sc * __uint_as_float(u2 & 0xFFFF0000u) + bb1.y;
    float v6 = sc * __uint_as_float(u3 << 16) + bb1.z;
    float v7 = sc * __uint_as_float(u3 & 0xFFFF0000u) + bb1.w;
    float m = fmaxf(fmaxf(fmaxf(v0, v1), fmaxf(v2, v3)),
                    fmaxf(fmaxf(v4, v5), fmaxf(v6, v7)));
#pragma unroll
    for (int o = 1; o <= 4; o <<= 1) m = fmaxf(m, __shfl_xor(m, o));
    float su = __expf(v0 - m) + __expf(v1 - m) + __expf(v2 - m) + __expf(v3 - m) +
               __expf(v4 - m) + __expf(v5 - m) + __expf(v6 - m) + __expf(v7 - m);
#pragma unroll
    for (int o = 1; o <= 4; o <<= 1) su += __shfl_xor(su, o);
    float ls = m + logf(su);
    if (gi == 0) {
        ((float4*)out)[(size_t)d * 16 + 2 * li] =
            make_float4(v0 - ls, v1 - ls, v2 - ls, v3 - ls);
        ((float4*)out)[(size_t)d * 16 + 2 * li + 1] =
            make_float4(v4 - ls, v5 - ls, v6 - ls, v7 - ls);
    }
}

extern "C" void kernel_launch(void* const* d_in, const int* in_sizes, int n_in,
                              void* d_out, int out_size, void* d_ws, size_t ws_size,
                              hipStream_t stream) {
    const float* x  = (const float*)d_in[0];
    const float* W1 = (const float*)d_in[1];
    const float* b1 = (const float*)d_in[2];
    const float* W2 = (const float*)d_in[3];
    const float* b2 = (const float*)d_in[4];
    const int* edge = (const int*)d_in[5];
    const int* src = edge;
    const int* dst = edge + N_EDGES;
    float* out = (float*)d_out;

    char* ws = (char*)d_ws;
    int*      cnt   = (int*)(ws + 0);            //   400,000
    float*    dinv  = (float*)(ws + 401408);     //   400,384 (MROWS, 16B-aligned)
    int*      rowp  = (int*)(ws + 802816);       //   400,004
    int*      part  = (int*)(ws + 1204224);      //     1,568 (SCAN_B+1; == boffs)
    int*      bcur  = (int*)(ws + 1205888);      //     1,564
    int*      srcs  = (int*)(ws + 1207552);      // 6,400,000
    unsigned* pairs = (unsigned*)(ws + 7607552); // 6,400,000 (packed 4B)
    short*    w1hi  = (short*)(ws + 14007552);   //    32,768
    short*    w1lo  = (short*)(ws + 14040320);   //    32,768
    short*    w2hi  = (short*)(ws + 14073088);   //    16,384
    short*    w2lo  = (short*)(ws + 14089472);   //    16,384
    short*    y1b   = (short*)(ws + 14106624);   // 25,624,576 (MROWS*128*2)
    short*    h1b   = (short*)(ws + 39731200);   // 25,624,576
    short*    y2b   = (short*)(ws + 65355776);   // 12,812,288 -> ends ~78 MB

    // ---- CSR build (bucketed counting sort; buckets == scan blocks) + dinv ----
    hipMemsetAsync(cnt, 0, 400000, stream);
    count_deg<<<512, 256, 0, stream>>>(dst, cnt);
    scan_reduce<<<SCAN_B, 256, 0, stream>>>(cnt, part, dinv);
    scan_part<<<1, 512, 0, stream>>>(part, bcur);
    scan_final<<<SCAN_B, 256, 0, stream>>>(cnt, part, rowp);
    bucket_scatter<<<(N_EDGES + CH - 1) / CH, 256, 0, stream>>>(src, dst, bcur, pairs);
    csr_fill_bucket<<<NB, 256, 0, stream>>>(pairs, part, rowp, srcs);

    // ---- weight conversion ----
    convert_w<<<(128 * 128 + 64 * 128 + 255) / 256, 256, 0, stream>>>(W1, W2, w1hi, w1lo,
                                                                      w2hi, w2lo);

    // ---- layer 1 ----
    gemm1_mfma<<<MROWS / 128, 256, 0, stream>>>(x, w1hi, w1lo, dinv, y1b);
    agg_relu<<<(N_NODES + 3) / 4, 256, 0, stream>>>(rowp, srcs, y1b, dinv, b1, h1b);

    // ---- layer 2 ----
    gemm2_mfma<<<MROWS / 128, 256, 0, stream>>>(h1b, w2hi, w2lo, dinv, y2b);
    agg_lsm<<<(N_NODES + 3) / 4, 256, 0, stream>>>(rowp, srcs, y2b, dinv, b2, out);
}

// Round 8
// 337.656 us; speedup vs baseline: 4.1343x; 1.1666x over previous
//
#include <hip/hip_runtime.h>
#include <math.h>

#define N_NODES 100000
#define N_EDGES 1600000
#define NB 391              // dst buckets (d>>8), 256 nodes each
#define MROWS 100096        // 782*128, padded row count for guard-free tiles
#define CH 3200             // edges per bucket_scatter block -> 500 blocks

typedef __attribute__((ext_vector_type(8))) short short8;  // 8 bf16 = 4 VGPRs
typedef __attribute__((ext_vector_type(4))) float f32x4;

__device__ __forceinline__ short f2b(float f) {            // fp32 -> bf16 RNE
    unsigned u = __float_as_uint(f);
    unsigned r = (u + 0x7FFFu + ((u >> 16) & 1u)) >> 16;
    return (short)r;
}
__device__ __forceinline__ float b2f(short s) {
    return __uint_as_float(((unsigned)(unsigned short)s) << 16);
}
__device__ __forceinline__ float lof(unsigned u) { return __uint_as_float(u << 16); }
__device__ __forceinline__ float hif(unsigned u) { return __uint_as_float(u & 0xFFFF0000u); }
__device__ __forceinline__ unsigned pk2(float a, float b) {
    return (unsigned)(unsigned short)f2b(a) | ((unsigned)(unsigned short)f2b(b) << 16);
}

// pack 8 fp32 -> 8 bf16 (RNE)
__device__ __forceinline__ short8 pack8(const float* __restrict__ p) {
    float4 v0 = ((const float4*)p)[0];
    float4 v1 = ((const float4*)p)[1];
    short8 h;
    h[0] = f2b(v0.x); h[1] = f2b(v0.y); h[2] = f2b(v0.z); h[3] = f2b(v0.w);
    h[4] = f2b(v1.x); h[5] = f2b(v1.y); h[6] = f2b(v1.z); h[7] = f2b(v1.w);
    return h;
}

// ---------- bucket histogram (LDS-staged: 1 LDS atomic per edge) ----------
__global__ __launch_bounds__(256) void bucket_count(const int* __restrict__ dst,
                                                    int* __restrict__ bcnt) {
    __shared__ int h[NB];
    int t = threadIdx.x;
    for (int i = t; i < NB; i += 256) h[i] = 0;
    __syncthreads();
    for (int e = blockIdx.x * 256 + t; e < N_EDGES; e += gridDim.x * 256)
        atomicAdd(&h[dst[e] >> 8], 1);
    __syncthreads();
    for (int i = t; i < NB; i += 256)
        if (h[i]) atomicAdd(&bcnt[i], h[i]);
}

// ---------- bucket-level exclusive scan (one block) ----------
__global__ __launch_bounds__(512) void bucket_scan(const int* __restrict__ bcnt,
                                                   int* __restrict__ boffs,
                                                   int* __restrict__ bcur) {
    __shared__ int s[512];
    int t = threadIdx.x;
    int v = (t < NB) ? bcnt[t] : 0;
    s[t] = v;
    __syncthreads();
    for (int off = 1; off < 512; off <<= 1) {
        int u = (t >= off) ? s[t - off] : 0;
        __syncthreads();
        s[t] += u;
        __syncthreads();
    }
    if (t < NB) {
        int ex = s[t] - v;
        boffs[t] = ex;
        bcur[t] = ex;
    }
    if (t == 0) boffs[NB] = N_EDGES;
}

// ---------- scatter edges into bucket-grouped packed list ----------
// packed word: (d&255)<<24 | src   (src < 2^24)
__global__ __launch_bounds__(256) void bucket_scatter(const int* __restrict__ src,
                                                      const int* __restrict__ dst,
                                                      int* __restrict__ bcur,
                                                      unsigned* __restrict__ pairs) {
    __shared__ unsigned lw[CH];
    __shared__ short lb[CH];
    __shared__ int cnt[NB];
    __shared__ int lstart[NB];
    int t = threadIdx.x;
    int e0 = blockIdx.x * CH;
    int n = min(CH, N_EDGES - e0);
    for (int i = t; i < NB; i += 256) cnt[i] = 0;
    __syncthreads();
    for (int i = t; i < n; i += 256) {
        int s = src[e0 + i], d = dst[e0 + i];
        lw[i] = ((unsigned)(d & 255) << 24) | (unsigned)s;
        int b = d >> 8;
        lb[i] = (short)b;
        atomicAdd(&cnt[b], 1);
    }
    __syncthreads();
    for (int b = t; b < NB; b += 256) {
        int c = cnt[b];
        lstart[b] = c ? atomicAdd(&bcur[b], c) : 0;
        cnt[b] = 0;  // reuse as local cursor
    }
    __syncthreads();
    for (int i = t; i < n; i += 256) {
        int b = lb[i];
        int lo = atomicAdd(&cnt[b], 1);
        pairs[lstart[b] + lo] = lw[i];
    }
}

// ---------- bucket-local CSR fill; ALSO derives rowp + dinv in-kernel ----------
__global__ __launch_bounds__(256) void csr_fill_bucket(const unsigned* __restrict__ pairs,
                                                       const int* __restrict__ boffs,
                                                       int* __restrict__ rowp,
                                                       float* __restrict__ dinv,
                                                       int* __restrict__ srcs) {
    __shared__ int lcnt[256];
    __shared__ int ls[256];
    int t = threadIdx.x;
    int b = blockIdx.x;
    int base = b << 8;
    lcnt[t] = 0;
    __syncthreads();
    int lo_e = boffs[b], hi_e = boffs[b + 1];
    // pass 1: per-node counts within this bucket
    for (int i = lo_e + t; i < hi_e; i += 256)
        atomicAdd(&lcnt[pairs[i] >> 24], 1);
    __syncthreads();
    int c = lcnt[t];
    // exclusive scan of counts
    ls[t] = c;
    __syncthreads();
    for (int off = 1; off < 256; off <<= 1) {
        int u = (t >= off) ? ls[t - off] : 0;
        __syncthreads();
        ls[t] += u;
        __syncthreads();
    }
    int rp = lo_e + ls[t] - c;   // global CSR start for node base+t
    int node = base + t;
    if (node < N_NODES) {
        rowp[node] = rp;
        dinv[node] = rsqrtf((float)(c + 1));
    }
    if (b == 0 && t == 0) rowp[N_NODES] = N_EDGES;
    __syncthreads();
    lcnt[t] = rp;  // reuse as global cursor
    __syncthreads();
    // pass 2: scatter srcs into L2-resident bucket window
    for (int i = lo_e + t; i < hi_e; i += 256) {
        unsigned p = pairs[i];
        int li = p >> 24;
        int pos = atomicAdd(&lcnt[li], 1);
        srcs[pos] = (int)(p & 0xFFFFFFu);
    }
}

// ---------- W1 [128][128] + W2 [128][64] fp32 -> Wt [N][128] split bf16 ----------
__global__ __launch_bounds__(256) void convert_w(const float* __restrict__ W1,
                                                 const float* __restrict__ W2,
                                                 short* __restrict__ w1hi,
                                                 short* __restrict__ w1lo,
                                                 short* __restrict__ w2hi,
                                                 short* __restrict__ w2lo) {
    int id = blockIdx.x * 256 + threadIdx.x;
    if (id < 128 * 128) {
        int n = id >> 7, k = id & 127;
        float v = W1[k * 128 + n];
        short h = f2b(v);
        w1hi[id] = h;
        w1lo[id] = f2b(v - b2f(h));
    } else if (id < 128 * 128 + 64 * 128) {
        int j = id - 128 * 128;
        int n = j >> 7, k = j & 127;
        float v = W2[k * 64 + n];
        short h = f2b(v);
        w2hi[j] = h;
        w2lo[j] = f2b(v - b2f(h));
    }
}

// ---------- layer-1 GEMM: Y1b = bf16((X @ W1) * dinv); A=bf16(X), B split ----------
__global__ __launch_bounds__(256) void gemm1_mfma(const float* __restrict__ X,
                                                  const short* __restrict__ Wthi,
                                                  const short* __restrict__ Wtlo,
                                                  const float* __restrict__ dinv,
                                                  short* __restrict__ Yb) {
    const int t = threadIdx.x;
    const int w = t >> 6, lane = t & 63;
    const int m = lane & 15, q = lane >> 4;
    const int r0 = blockIdx.x * 128 + w * 32;
    const int ra = min(r0 + m, N_NODES - 1);
    const int rb = min(r0 + 16 + m, N_NODES - 1);

    f32x4 acc[2][8];
#pragma unroll
    for (int i = 0; i < 2; ++i)
#pragma unroll
        for (int c = 0; c < 8; ++c) acc[i][c] = (f32x4)(0.f);

#pragma unroll
    for (int kk = 0; kk < 4; ++kk) {
        const int koff = kk * 32 + q * 8;
        short8 ah0 = pack8(X + (size_t)ra * 128 + koff);
        short8 ah1 = pack8(X + (size_t)rb * 128 + koff);
#pragma unroll
        for (int c = 0; c < 8; ++c) {
            short8 bh = *(const short8*)(Wthi + (c * 16 + m) * 128 + koff);
            short8 bl = *(const short8*)(Wtlo + (c * 16 + m) * 128 + koff);
            acc[0][c] = __builtin_amdgcn_mfma_f32_16x16x32_bf16(ah0, bh, acc[0][c], 0, 0, 0);
            acc[1][c] = __builtin_amdgcn_mfma_f32_16x16x32_bf16(ah1, bh, acc[1][c], 0, 0, 0);
            acc[0][c] = __builtin_amdgcn_mfma_f32_16x16x32_bf16(ah0, bl, acc[0][c], 0, 0, 0);
            acc[1][c] = __builtin_amdgcn_mfma_f32_16x16x32_bf16(ah1, bl, acc[1][c], 0, 0, 0);
        }
    }

    const int rb0 = r0 + q * 4;
    const int rb1 = r0 + 16 + q * 4;
    f32x4 dv0 = *(const f32x4*)(dinv + rb0);
    f32x4 dv1 = *(const f32x4*)(dinv + rb1);
#pragma unroll
    for (int c = 0; c < 8; ++c) {
        const int col = c * 16 + m;
#pragma unroll
        for (int r = 0; r < 4; ++r) {
            int row = rb0 + r;
            if (row < N_NODES) Yb[(size_t)row * 128 + col] = f2b(acc[0][c][r] * dv0[r]);
            row = rb1 + r;
            if (row < N_NODES) Yb[(size_t)row * 128 + col] = f2b(acc[1][c][r] * dv1[r]);
        }
    }
}

// ---------- layer-2 GEMM: Y2b = bf16((H @ W2) * dinv), H plain bf16 ----------
__global__ __launch_bounds__(256) void gemm2_mfma(const short* __restrict__ H,
                                                  const short* __restrict__ Wthi,
                                                  const short* __restrict__ Wtlo,
                                                  const float* __restrict__ dinv,
                                                  short* __restrict__ Yb) {
    const int t = threadIdx.x;
    const int w = t >> 6, lane = t & 63;
    const int m = lane & 15, q = lane >> 4;
    const int r0 = blockIdx.x * 128 + w * 32;

    f32x4 acc[2][4];
#pragma unroll
    for (int i = 0; i < 2; ++i)
#pragma unroll
        for (int c = 0; c < 4; ++c) acc[i][c] = (f32x4)(0.f);

#pragma unroll
    for (int kk = 0; kk < 4; ++kk) {
        const int koff = kk * 32 + q * 8;
        short8 ah0 = *(const short8*)(H + (size_t)(r0 + m) * 128 + koff);
        short8 ah1 = *(const short8*)(H + (size_t)(r0 + 16 + m) * 128 + koff);
#pragma unroll
        for (int c = 0; c < 4; ++c) {
            short8 bh = *(const short8*)(Wthi + (c * 16 + m) * 128 + koff);
            short8 bl = *(const short8*)(Wtlo + (c * 16 + m) * 128 + koff);
            acc[0][c] = __builtin_amdgcn_mfma_f32_16x16x32_bf16(ah0, bh, acc[0][c], 0, 0, 0);
            acc[1][c] = __builtin_amdgcn_mfma_f32_16x16x32_bf16(ah1, bh, acc[1][c], 0, 0, 0);
            acc[0][c] = __builtin_amdgcn_mfma_f32_16x16x32_bf16(ah0, bl, acc[0][c], 0, 0, 0);
            acc[1][c] = __builtin_amdgcn_mfma_f32_16x16x32_bf16(ah1, bl, acc[1][c], 0, 0, 0);
        }
    }

    const int rb0 = r0 + q * 4;
    const int rb1 = r0 + 16 + q * 4;
    f32x4 dv0 = *(const f32x4*)(dinv + rb0);
    f32x4 dv1 = *(const f32x4*)(dinv + rb1);
#pragma unroll
    for (int c = 0; c < 4; ++c) {
        const int col = c * 16 + m;
#pragma unroll
        for (int r = 0; r < 4; ++r) {
            int row = rb0 + r;
            if (row < N_NODES) Yb[(size_t)row * 64 + col] = f2b(acc[0][c][r] * dv0[r]);
            row = rb1 + r;
            if (row < N_NODES) Yb[(size_t)row * 64 + col] = f2b(acc[1][c][r] * dv1[r]);
        }
    }
}

// ---------- CSR aggregation, K=128: quarter-wave/edge, f32 accumulate ----------
__global__ __launch_bounds__(256) void agg_relu(const int* __restrict__ rowp,
                                                const int* __restrict__ srcs,
                                                const short* __restrict__ Yb,
                                                const float* __restrict__ dinv,
                                                const float* __restrict__ b,
                                                short* __restrict__ Hb) {
    int t = threadIdx.x;
    int lane = t & 63, w = t >> 6;
    int qi = lane >> 4, li = lane & 15;      // 4 quarter-groups of 16 lanes
    int d = blockIdx.x * 4 + w;
    if (d >= N_NODES) return;
    const uint4* Y4 = (const uint4*)Yb;      // row = 16 uint4 (128 bf16)
    float a[8] = {0.f, 0.f, 0.f, 0.f, 0.f, 0.f, 0.f, 0.f};
    if (qi == 0) {                            // self loop into group 0
        uint4 u = Y4[(size_t)d * 16 + li];
        a[0] = lof(u.x); a[1] = hif(u.x); a[2] = lof(u.y); a[3] = hif(u.y);
        a[4] = lof(u.z); a[5] = hif(u.z); a[6] = lof(u.w); a[7] = hif(u.w);
    }
    int e = rowp[d], end = rowp[d + 1];
    for (; e + 8 <= end; e += 8) {            // 8 edges: 2 loads in flight
        int s0 = srcs[e + qi], s1 = srcs[e + 4 + qi];
        uint4 u0 = Y4[(size_t)s0 * 16 + li];
        uint4 u1 = Y4[(size_t)s1 * 16 + li];
        a[0] += lof(u0.x) + lof(u1.x); a[1] += hif(u0.x) + hif(u1.x);
        a[2] += lof(u0.y) + lof(u1.y); a[3] += hif(u0.y) + hif(u1.y);
        a[4] += lof(u0.z) + lof(u1.z); a[5] += hif(u0.z) + hif(u1.z);
        a[6] += lof(u0.w) + lof(u1.w); a[7] += hif(u0.w) + hif(u1.w);
    }
    for (; e < end; e += 4) {                 // masked remainder, 4 edges/step
        int idx = e + qi;
        int s = srcs[(idx < end) ? idx : e];
        uint4 u = Y4[(size_t)s * 16 + li];
        if (idx < end) {
            a[0] += lof(u.x); a[1] += hif(u.x); a[2] += lof(u.y); a[3] += hif(u.y);
            a[4] += lof(u.z); a[5] += hif(u.z); a[6] += lof(u.w); a[7] += hif(u.w);
        }
    }
    // merge quarter-groups
#pragma unroll
    for (int i = 0; i < 8; ++i) {
        a[i] += __shfl_xor(a[i], 16);
        a[i] += __shfl_xor(a[i], 32);
    }
    if (qi == 0) {                            // epilogue: feats 8*li .. 8*li+7
        float sc = dinv[d];
        float4 bb0 = ((const float4*)b)[2 * li];
        float4 bb1 = ((const float4*)b)[2 * li + 1];
        float v0 = fmaxf(sc * a[0] + bb0.x, 0.f);
        float v1 = fmaxf(sc * a[1] + bb0.y, 0.f);
        float v2 = fmaxf(sc * a[2] + bb0.z, 0.f);
        float v3 = fmaxf(sc * a[3] + bb0.w, 0.f);
        float v4 = fmaxf(sc * a[4] + bb1.x, 0.f);
        float v5 = fmaxf(sc * a[5] + bb1.y, 0.f);
        float v6 = fmaxf(sc * a[6] + bb1.z, 0.f);
        float v7 = fmaxf(sc * a[7] + bb1.w, 0.f);
        uint4 o = make_uint4(pk2(v0, v1), pk2(v2, v3), pk2(v4, v5), pk2(v6, v7));
        ((uint4*)Hb)[(size_t)d * 16 + li] = o;
    }
}

// ---------- CSR aggregation, K=64: eighth-wave/edge, f32 acc + log_softmax ----------
__global__ __launch_bounds__(256) void agg_lsm(const int* __restrict__ rowp,
                                               const int* __restrict__ srcs,
                                               const short* __restrict__ Yb,
                                               const float* __restrict__ dinv,
                                               const float* __restrict__ b,
                                               float* __restrict__ out) {
    int t = threadIdx.x;
    int lane = t & 63, w = t >> 6;
    int gi = lane >> 3, li = lane & 7;        // 8 octet-groups of 8 lanes
    int d = blockIdx.x * 4 + w;
    if (d >= N_NODES) return;
    const uint4* Y4 = (const uint4*)Yb;       // row = 8 uint4 (64 bf16)
    float a[8] = {0.f, 0.f, 0.f, 0.f, 0.f, 0.f, 0.f, 0.f};
    if (gi == 0) {                             // self loop
        uint4 u = Y4[(size_t)d * 8 + li];
        a[0] = lof(u.x); a[1] = hif(u.x); a[2] = lof(u.y); a[3] = hif(u.y);
        a[4] = lof(u.z); a[5] = hif(u.z); a[6] = lof(u.w); a[7] = hif(u.w);
    }
    int e = rowp[d], end = rowp[d + 1];
    for (; e + 16 <= end; e += 16) {           // 16 edges: 2 loads in flight
        int s0 = srcs[e + gi], s1 = srcs[e + 8 + gi];
        uint4 u0 = Y4[(size_t)s0 * 8 + li];
        uint4 u1 = Y4[(size_t)s1 * 8 + li];
        a[0] += lof(u0.x) + lof(u1.x); a[1] += hif(u0.x) + hif(u1.x);
        a[2] += lof(u0.y) + lof(u1.y); a[3] += hif(u0.y) + hif(u1.y);
        a[4] += lof(u0.z) + lof(u1.z); a[5] += hif(u0.z) + hif(u1.z);
        a[6] += lof(u0.w) + lof(u1.w); a[7] += hif(u0.w) + hif(u1.w);
    }
    for (; e < end; e += 8) {                  // masked remainder, 8 edges/step
        int idx = e + gi;
        int s = srcs[(idx < end) ? idx : e];
        uint4 u = Y4[(size_t)s * 8 + li];
        if (idx < end) {
            a[0] += lof(u.x); a[1] += hif(u.x); a[2] += lof(u.y); a[3] += hif(u.y);
            a[4] += lof(u.z); a[5] += hif(u.z); a[6] += lof(u.w); a[7] += hif(u.w);
        }
    }
    // merge octet-groups (levels 8, 16, 32) -> all lanes hold totals
#pragma unroll
    for (int i = 0; i < 8; ++i) {
        a[i] += __shfl_xor(a[i], 8);
        a[i] += __shfl_xor(a[i], 16);
        a[i] += __shfl_xor(a[i], 32);
    }
    // epilogue: lane li holds feats 8*li .. 8*li+7 (identical across octets)
    float sc = dinv[d];
    float4 bb0 = ((const float4*)b)[2 * li];
    float4 bb1 = ((const float4*)b)[2 * li + 1];
    float v0 = sc * a[0] + bb0.x;
    float v1 = sc * a[1] + bb0.y;
    float v2 = sc * a[2] + bb0.z;
    float v3 = sc * a[3] + bb0.w;
    float v4 = sc * a[4] + bb1.x;
    float v5 = sc * a[5] + bb1.y;
    float v6 = sc * a[6] + bb1.z;
    float v7 = sc * a[7] + bb1.w;
    float m = fmaxf(fmaxf(fmaxf(v0, v1), fmaxf(v2, v3)),
                    fmaxf(fmaxf(v4, v5), fmaxf(v6, v7)));
#pragma unroll
    for (int o = 1; o <= 4; o <<= 1) m = fmaxf(m, __shfl_xor(m, o));
    float su = __expf(v0 - m) + __expf(v1 - m) + __expf(v2 - m) + __expf(v3 - m) +
               __expf(v4 - m) + __expf(v5 - m) + __expf(v6 - m) + __expf(v7 - m);
#pragma unroll
    for (int o = 1; o <= 4; o <<= 1) su += __shfl_xor(su, o);
    float ls = m + logf(su);
    if (gi == 0) {
        ((float4*)out)[(size_t)d * 16 + 2 * li] =
            make_float4(v0 - ls, v1 - ls, v2 - ls, v3 - ls);
        ((float4*)out)[(size_t)d * 16 + 2 * li + 1] =
            make_float4(v4 - ls, v5 - ls, v6 - ls, v7 - ls);
    }
}

extern "C" void kernel_launch(void* const* d_in, const int* in_sizes, int n_in,
                              void* d_out, int out_size, void* d_ws, size_t ws_size,
                              hipStream_t stream) {
    const float* x  = (const float*)d_in[0];
    const float* W1 = (const float*)d_in[1];
    const float* b1 = (const float*)d_in[2];
    const float* W2 = (const float*)d_in[3];
    const float* b2 = (const float*)d_in[4];
    const int* edge = (const int*)d_in[5];
    const int* src = edge;
    const int* dst = edge + N_EDGES;
    float* out = (float*)d_out;

    char* ws = (char*)d_ws;
    int*      bcnt  = (int*)(ws + 0);            //     1,564
    int*      boffs = (int*)(ws + 2048);         //     1,568
    int*      bcur  = (int*)(ws + 4096);         //     1,564
    float*    dinv  = (float*)(ws + 6144);       //   400,384 (MROWS, 16B-aligned)
    int*      rowp  = (int*)(ws + 406528);       //   400,008
    int*      srcs  = (int*)(ws + 806912);       // 6,400,000
    unsigned* pairs = (unsigned*)(ws + 7206912); // 6,400,000 (packed 4B)
    short*    w1hi  = (short*)(ws + 13606912);   //    32,768
    short*    w1lo  = (short*)(ws + 13639680);   //    32,768
    short*    w2hi  = (short*)(ws + 13672448);   //    16,384
    short*    w2lo  = (short*)(ws + 13688832);   //    16,384
    short*    y1b   = (short*)(ws + 13705216);   // 25,624,576 (MROWS*128*2)
    short*    h1b   = (short*)(ws + 39329792);   // 25,624,576
    short*    y2b   = (short*)(ws + 64954368);   // 12,812,288 -> ends ~74 MB

    // ---- CSR build: bucket histogram -> scan -> scatter -> bucket-local fill ----
    // (rowp + dinv derived inside csr_fill_bucket; no global per-node atomics)
    hipMemsetAsync(bcnt, 0, NB * sizeof(int), stream);
    bucket_count<<<512, 256, 0, stream>>>(dst, bcnt);
    bucket_scan<<<1, 512, 0, stream>>>(bcnt, boffs, bcur);
    bucket_scatter<<<(N_EDGES + CH - 1) / CH, 256, 0, stream>>>(src, dst, bcur, pairs);
    csr_fill_bucket<<<NB, 256, 0, stream>>>(pairs, boffs, rowp, dinv, srcs);

    // ---- weight conversion ----
    convert_w<<<(128 * 128 + 64 * 128 + 255) / 256, 256, 0, stream>>>(W1, W2, w1hi, w1lo,
                                                                      w2hi, w2lo);

    // ---- layer 1 ----
    gemm1_mfma<<<MROWS / 128, 256, 0, stream>>>(x, w1hi, w1lo, dinv, y1b);
    agg_relu<<<(N_NODES + 3) / 4, 256, 0, stream>>>(rowp, srcs, y1b, dinv, b1, h1b);

    // ---- layer 2 ----
    gemm2_mfma<<<MROWS / 128, 256, 0, stream>>>(h1b, w2hi, w2lo, dinv, y2b);
    agg_lsm<<<(N_NODES + 3) / 4, 256, 0, stream>>>(rowp, srcs, y2b, dinv, b2, out);
}